// Round 12
// baseline (569.554 us; speedup 1.0000x reference)
//
#include <hip/hip_runtime.h>
#include <hip/hip_bf16.h>
#include <math.h>

// Qwen3.5 attention block, bf16-MFMA everywhere.
// cvt(hs), transpose_cvt(w_qkv) -> gemm256 (QKV, 256^2 4-phase counted-vmcnt)
// -> vt_transpose -> norm_rope_cvt (wave-parallel) ->
// flash_attn_mfma v10 -> transpose_cvt(w_o) -> gemm_bf16 (out, 128^2).

namespace {
constexpr int kT   = 4096;
constexpr int kHid = 2048;
constexpr int kH   = 16;
constexpr int kHkv = 2;
constexpr int kD   = 128;
constexpr int kNqkv = (2 * kH + 2 * kHkv) * kD;  // 4608 floats per row
constexpr int kQsz  = 2 * kH * kD;               // 4096
constexpr int kRowU = kNqkv * 2;                 // 9216 ushorts per row
constexpr float kEps = 1e-6f;
constexpr float kScale = 0.08838834764831845f;   // 128^-0.5
}

typedef __attribute__((ext_vector_type(8))) short short8;
typedef __attribute__((ext_vector_type(4))) float floatx4;

__device__ inline unsigned short f2bf(float x) {
  unsigned u = __float_as_uint(x);
  u = (u + 0x7fffu + ((u >> 16) & 1u)) >> 16;
  return (unsigned short)u;
}

__device__ inline void gload_lds16(const void* g, void* l) {
  typedef const __attribute__((address_space(1))) unsigned GQ;
  typedef __attribute__((address_space(3))) unsigned LQ;
  __builtin_amdgcn_global_load_lds((GQ*)g, (LQ*)l, 16, 0, 0);
}

// ---- fp32 -> bf16 elementwise ----
__global__ __launch_bounds__(256)
void cvt_bf16(const float* __restrict__ in, unsigned short* __restrict__ out,
              long nelem) {
  long i = ((long)blockIdx.x * 256 + threadIdx.x) * 4;
  if (i >= nelem) return;
  float4 v = *(const float4*)(in + i);
  unsigned long long p = (unsigned long long)f2bf(v.x) |
                         ((unsigned long long)f2bf(v.y) << 16) |
                         ((unsigned long long)f2bf(v.z) << 32) |
                         ((unsigned long long)f2bf(v.w) << 48);
  *(unsigned long long*)(out + i) = p;
}

// ---- fp32 [R][C] -> bf16 [C][R] tiled transpose ----
__global__ __launch_bounds__(256)
void transpose_cvt(const float* __restrict__ in, unsigned short* __restrict__ out,
                   int R, int C) {
  __shared__ float t[32][33];
  const int bx = blockIdx.x * 32;
  const int by = blockIdx.y * 32;
  const int x = threadIdx.x & 31, y = threadIdx.x >> 5;
#pragma unroll
  for (int j = 0; j < 4; ++j)
    t[y * 4 + j][x] = in[(long)(by + y * 4 + j) * C + bx + x];
  __syncthreads();
#pragma unroll
  for (int j = 0; j < 4; ++j)
    out[(long)(bx + y * 4 + j) * R + by + x] = f2bf(t[x][y * 4 + j]);
}

// ---- V^T pre-transpose: qkv fp32 V (rows t, 256 cols) -> VtG bf16 [256][T] ----
__global__ __launch_bounds__(256)
void vt_transpose(const float* __restrict__ qkv, unsigned short* __restrict__ VtG) {
  __shared__ float t[32][33];
  const int t0 = blockIdx.x * 32;
  const int c0 = blockIdx.y * 32;
  const int x = threadIdx.x & 31, y = threadIdx.x >> 5;
#pragma unroll
  for (int j = 0; j < 4; ++j)
    t[y * 4 + j][x] = qkv[(long)(t0 + y * 4 + j) * kNqkv + 4352 + c0 + x];
  __syncthreads();
#pragma unroll
  for (int j = 0; j < 4; ++j)
    VtG[(long)(c0 + y * 4 + j) * kT + t0 + x] = f2bf(t[x][y * 4 + j]);
}

// ---- gemm256: C[M,N] fp32 = A[M,K]bf16 @ Bt[N,K]bf16^T. ----
// BM=BN=256, BK=64 split into 2 K-halves; 512 thr = 8 waves (2m x 4n),
// per-wave 128x64 out, acc[8][4]. LDS chunk-major [4 chunks][256 rows] per
// (parity, khalf): staging (gload_lds, linear dest / per-lane source) and
// fragment reads are both contiguous -> conflict-free, no swizzle.
// 4 phases/tile: each stages ONE half-tile of t+1 then runs a 16-MFMA
// cluster (setprio). Counted vmcnt(4) + raw s_barrier at mid-tile (kh1
// ready) and boundary (next kh0 ready) -> pipeline never drains mid-loop.
__global__ __launch_bounds__(512)
void gemm256(const unsigned short* __restrict__ A,
             const unsigned short* __restrict__ Bt, float* __restrict__ C,
             int M, int N, int K) {
  __shared__ __align__(16) unsigned short As[2][2][8192];  // [parity][khalf]
  __shared__ __align__(16) unsigned short Bs[2][2][8192];
  const int tid = threadIdx.x;
  const int lane = tid & 63;
  const int w = tid >> 6;            // 0..7
  const int wm = w >> 2, wn = w & 3; // wave tile: rows wm*128, cols wn*64
  const int n16 = lane & 15, quad = lane >> 4;
  const long bm = (long)blockIdx.x * 256, bn = (long)blockIdx.y * 256;
  const int NT = K >> 6;

  floatx4 acc[8][4];
  floatx4 zero = {0.f, 0.f, 0.f, 0.f};
#pragma unroll
  for (int mf = 0; mf < 8; ++mf)
#pragma unroll
    for (int nf = 0; nf < 4; ++nf) acc[mf][nf] = zero;

  // stage one k-half (256 rows x 32 k = 1024 chunks) into chunk-major LDS
  auto stageA = [&](int p, int kh, int kt) {
#pragma unroll
    for (int it = 0; it < 2; ++it) {
      int ci = it * 512 + tid;            // 0..1023
      int r = ci & 255, cpos = ci >> 8;   // row, chunk col within khalf
      gload_lds16(A + (bm + r) * (long)K + kt * 64 + kh * 32 + cpos * 8,
                  &As[p][kh][(it * 512 + w * 64) * 8]);
    }
  };
  auto stageB = [&](int p, int kh, int kt) {
#pragma unroll
    for (int it = 0; it < 2; ++it) {
      int ci = it * 512 + tid;
      int r = ci & 255, cpos = ci >> 8;
      gload_lds16(Bt + (bn + r) * (long)K + kt * 64 + kh * 32 + cpos * 8,
                  &Bs[p][kh][(it * 512 + w * 64) * 8]);
    }
  };

  // prologue: tile 0 fully staged
  stageA(0, 0, 0); stageB(0, 0, 0); stageA(0, 1, 0); stageB(0, 1, 0);
  __asm__ volatile("s_waitcnt vmcnt(0)" ::: "memory");
  __builtin_amdgcn_s_barrier();
  __builtin_amdgcn_sched_barrier(0);

  for (int t = 0; t < NT; ++t) {
    const int p = t & 1, ps = p ^ 1;
    const bool pre = (t + 1 < NT);
    short8 af[8], bf[2];

    // ---- phase 0: ks=0, nf 0-1 ----
    if (pre) stageA(ps, 0, t + 1);
#pragma unroll
    for (int mf = 0; mf < 8; ++mf)
      af[mf] = *(const short8*)(&As[p][0][(quad * 256 + wm * 128 + mf * 16 + n16) * 8]);
#pragma unroll
    for (int nf = 0; nf < 2; ++nf)
      bf[nf] = *(const short8*)(&Bs[p][0][(quad * 256 + wn * 64 + nf * 16 + n16) * 8]);
    __builtin_amdgcn_s_setprio(1);
#pragma unroll
    for (int mf = 0; mf < 8; ++mf)
#pragma unroll
      for (int nf = 0; nf < 2; ++nf)
        acc[mf][nf] = __builtin_amdgcn_mfma_f32_16x16x32_bf16(af[mf], bf[nf], acc[mf][nf], 0, 0, 0);
    __builtin_amdgcn_s_setprio(0);

    // ---- phase 1: ks=0, nf 2-3 (af reused) ----
    if (pre) stageB(ps, 0, t + 1);
#pragma unroll
    for (int nf = 0; nf < 2; ++nf)
      bf[nf] = *(const short8*)(&Bs[p][0][(quad * 256 + wn * 64 + (nf + 2) * 16 + n16) * 8]);
    __builtin_amdgcn_s_setprio(1);
#pragma unroll
    for (int mf = 0; mf < 8; ++mf)
#pragma unroll
      for (int nf = 0; nf < 2; ++nf)
        acc[mf][nf + 2] = __builtin_amdgcn_mfma_f32_16x16x32_bf16(af[mf], bf[nf], acc[mf][nf + 2], 0, 0, 0);
    __builtin_amdgcn_s_setprio(0);

    // ---- mid-tile: this tile's kh1 must be landed (all waves) ----
    if (pre) { __asm__ volatile("s_waitcnt vmcnt(4)" ::: "memory"); }
    else     { __asm__ volatile("s_waitcnt vmcnt(0)" ::: "memory"); }
    __builtin_amdgcn_s_barrier();
    __builtin_amdgcn_sched_barrier(0);

    // ---- phase 2: ks=1, nf 0-1 ----
    if (pre) stageA(ps, 1, t + 1);
#pragma unroll
    for (int mf = 0; mf < 8; ++mf)
      af[mf] = *(const short8*)(&As[p][1][(quad * 256 + wm * 128 + mf * 16 + n16) * 8]);
#pragma unroll
    for (int nf = 0; nf < 2; ++nf)
      bf[nf] = *(const short8*)(&Bs[p][1][(quad * 256 + wn * 64 + nf * 16 + n16) * 8]);
    __builtin_amdgcn_s_setprio(1);
#pragma unroll
    for (int mf = 0; mf < 8; ++mf)
#pragma unroll
      for (int nf = 0; nf < 2; ++nf)
        acc[mf][nf] = __builtin_amdgcn_mfma_f32_16x16x32_bf16(af[mf], bf[nf], acc[mf][nf], 0, 0, 0);
    __builtin_amdgcn_s_setprio(0);

    // ---- phase 3: ks=1, nf 2-3 ----
    if (pre) stageB(ps, 1, t + 1);
#pragma unroll
    for (int nf = 0; nf < 2; ++nf)
      bf[nf] = *(const short8*)(&Bs[p][1][(quad * 256 + wn * 64 + (nf + 2) * 16 + n16) * 8]);
    __builtin_amdgcn_s_setprio(1);
#pragma unroll
    for (int mf = 0; mf < 8; ++mf)
#pragma unroll
      for (int nf = 0; nf < 2; ++nf)
        acc[mf][nf + 2] = __builtin_amdgcn_mfma_f32_16x16x32_bf16(af[mf], bf[nf], acc[mf][nf + 2], 0, 0, 0);
    __builtin_amdgcn_s_setprio(0);

    // ---- boundary: next tile's kh0 must be landed; kh1' stays in flight ----
    if (pre) {
      __asm__ volatile("s_waitcnt vmcnt(4)" ::: "memory");
      __builtin_amdgcn_s_barrier();
      __builtin_amdgcn_sched_barrier(0);
    }
  }

  // epilogue
#pragma unroll
  for (int mf = 0; mf < 8; ++mf)
#pragma unroll
    for (int nf = 0; nf < 4; ++nf)
#pragma unroll
      for (int r = 0; r < 4; ++r)
        C[(bm + wm * 128 + mf * 16 + quad * 4 + r) * (long)N + bn + wn * 64 + nf * 16 + n16] =
            acc[mf][nf][r];
}

// ---- C[M,N] fp32 = A[M,K]bf16 @ Bt[N,K]bf16^T. 128x128 tile, BK=64. ----
__global__ __launch_bounds__(256)
void gemm_bf16(const unsigned short* __restrict__ A,
               const unsigned short* __restrict__ Bt, float* __restrict__ C,
               int M, int N, int K) {
  __shared__ __align__(16) unsigned short As[128 * 64];
  __shared__ __align__(16) unsigned short Bs[128 * 64];
  const int tid = threadIdx.x;
  const int lane = tid & 63;
  const int w = tid >> 6;
  const int wr = w >> 1, wc = w & 1;
  const int n = lane & 15;
  const int quad = lane >> 4;
  const long bm = (long)blockIdx.x * 128, bn = (long)blockIdx.y * 128;

  floatx4 acc[4][4];
  floatx4 zero = {0.f, 0.f, 0.f, 0.f};
#pragma unroll
  for (int a = 0; a < 4; ++a)
#pragma unroll
    for (int b = 0; b < 4; ++b) acc[a][b] = zero;

  for (int k0 = 0; k0 < K; k0 += 64) {
    __syncthreads();
#pragma unroll
    for (int it = 0; it < 4; ++it) {
      int ci = it * 256 + tid;            // 16B chunk id 0..1023
      int r = ci >> 3, c = ci & 7;
      int cg = c ^ (r & 7);               // global chunk for this slot
      gload_lds16(A + (bm + r) * (long)K + k0 + cg * 8, As + (it * 256 + w * 64) * 8);
      gload_lds16(Bt + (bn + r) * (long)K + k0 + cg * 8, Bs + (it * 256 + w * 64) * 8);
    }
    __syncthreads();

#pragma unroll
    for (int ks = 0; ks < 2; ++ks) {
      short8 af[4], bf[4];
#pragma unroll
      for (int a = 0; a < 4; ++a) {
        int m = wr * 64 + a * 16 + n;
        af[a] = *(const short8*)(As + m * 64 + ((4 * ks + quad) ^ (m & 7)) * 8);
      }
#pragma unroll
      for (int b = 0; b < 4; ++b) {
        int nn = wc * 64 + b * 16 + n;
        bf[b] = *(const short8*)(Bs + nn * 64 + ((4 * ks + quad) ^ (nn & 7)) * 8);
      }
#pragma unroll
      for (int a = 0; a < 4; ++a)
#pragma unroll
        for (int b = 0; b < 4; ++b)
          acc[a][b] = __builtin_amdgcn_mfma_f32_16x16x32_bf16(af[a], bf[b], acc[a][b], 0, 0, 0);
    }
  }
#pragma unroll
  for (int a = 0; a < 4; ++a)
#pragma unroll
    for (int b = 0; b < 4; ++b)
#pragma unroll
      for (int r = 0; r < 4; ++r)
        C[(bm + wr * 64 + a * 16 + quad * 4 + r) * (long)N + bn + wc * 64 + b * 16 + n] =
            acc[a][b][r];
}

// ------- RMSNorm + RoPE + bf16 pack (q,k), wave-parallel, barrier-free -------
__global__ __launch_bounds__(256)
void norm_rope_cvt(float* qkv, const float* __restrict__ cosb,
                   const float* __restrict__ sinb, const float* __restrict__ qw,
                   const float* __restrict__ kw) {
  unsigned short* qkvu = (unsigned short*)qkv;
  const int lane = threadIdx.x & 63;
  const int wslot = blockIdx.x * 4 + (threadIdx.x >> 6);
  const int nslots = gridDim.x * 4;
  for (int task = wslot; task < kT * 18; task += nslots) {
    const int t = task / 18;
    const int h = task % 18;
    const bool isq = (h < kH);
    const long base = (long)t * kNqkv + (isq ? h * 2 * kD : kQsz + (h - kH) * kD);
    float xlo = qkv[base + lane];
    float xhi = qkv[base + 64 + lane];
    float v = xlo * xlo + xhi * xhi;
#pragma unroll
    for (int off = 1; off < 64; off <<= 1) v += __shfl_xor(v, off, 64);
    float rms = rsqrtf(v * (1.0f / kD) + kEps);
    const float* wv = isq ? qw : kw;
    float nlo = xlo * rms * wv[lane];
    float nhi = xhi * rms * wv[64 + lane];
    float clo = cosb[t * kD + lane], chi = cosb[t * kD + 64 + lane];
    float slo = sinb[t * kD + lane], shi = sinb[t * kD + 64 + lane];
    float rlo = nlo * clo - nhi * slo;   // rot(lo) = -x[l+64]
    float rhi = nhi * chi + nlo * shi;   // rot(hi) = +x[l]
    if (isq) {
      float glo = qkv[base + kD + lane];
      float ghi = qkv[base + kD + 64 + lane];
      qkv[base + kD + lane] = 1.0f / (1.0f + __expf(-glo));
      qkv[base + kD + 64 + lane] = 1.0f / (1.0f + __expf(-ghi));
      qkvu[(long)t * kRowU + 512 * h + lane] = f2bf(rlo);
      qkvu[(long)t * kRowU + 512 * h + 64 + lane] = f2bf(rhi);
    } else {
      qkvu[(long)t * kRowU + 8192 + 256 * (h - kH) + lane] = f2bf(rlo);
      qkvu[(long)t * kRowU + 8192 + 256 * (h - kH) + 64 + lane] = f2bf(rhi);
    }
  }
}

// ---------------- bf16 MFMA flash attention v10 (best: 166.7us) -------------
// v3 structure + dedicated Ps buffer (barrier (3) removed; 2 barriers/tile).
__global__ __launch_bounds__(256)
void flash_attn_mfma(const unsigned short* qkvu, const float* qkvf,
                     const unsigned short* VtG, unsigned short* __restrict__ og) {
  __shared__ __align__(16) unsigned short Ks[64 * 128];  // K tile (swizzled)
  __shared__ __align__(16) unsigned short Vt[128 * 64];  // V^T tile (swizzled)
  __shared__ __align__(16) unsigned short Ps[128 * 64];  // P tile (row-swizzled)

  const int tid = threadIdx.x;
  const int lane = tid & 63;
  const int w = tid >> 6;
  const int n = lane & 15;
  const int quad = lane >> 4;
  const int g = blockIdx.x;
  const int h = g & 15;
  const int bm = 31 - (g >> 4);   // heavy-first
  const int hk = h >> 3;
  const int q0 = bm * 128;

  short8 qf[2][4];
#pragma unroll
  for (int mt = 0; mt < 2; ++mt) {
    const unsigned short* qrow =
        qkvu + (long)(q0 + 32 * w + 16 * mt + n) * kRowU + 512 * h;
#pragma unroll
    for (int ks = 0; ks < 4; ++ks)
      qf[mt][ks] = *(const short8*)(qrow + 32 * ks + 8 * quad);
  }
  short8 lfrag;  // B-frag: col 0 = ones -> row-sum accumulator
  {
    short o = (n == 0) ? (short)0x3F80 : (short)0;
    lfrag = (short8){o, o, o, o, o, o, o, o};
  }

  floatx4 O[2][8];
  floatx4 Ol[2];
  floatx4 zero = {0.f, 0.f, 0.f, 0.f};
#pragma unroll
  for (int mt = 0; mt < 2; ++mt) {
    Ol[mt] = zero;
#pragma unroll
    for (int dt = 0; dt < 8; ++dt) O[mt][dt] = zero;
  }

  const int kn_end = 2 * bm + 1;
  for (int kn = 0; kn <= kn_end; ++kn) {
    __syncthreads();  // (1) prev QK+PV reads done before restage
    // stage K: 64 rows x 128 d, chunk swizzle c ^ (r&15)
#pragma unroll
    for (int it = 0; it < 4; ++it) {
      int pc = (w * 4 + it) * 64 + lane;
      int r = pc >> 4, c = pc & 15;
      int lc = c ^ (r & 15);
      gload_lds16(qkvu + (long)(kn * 64 + r) * kRowU + 8192 + 256 * hk + 8 * lc,
                  Ks + (w * 4 + it) * 512);
    }
    // stage V^T: 128 rows (d) x 64 keys, chunk swizzle c ^ (d&7)
#pragma unroll
    for (int it = 0; it < 4; ++it) {
      int pc = (w * 4 + it) * 64 + lane;
      int d = pc >> 3, c = pc & 7;
      int lc = c ^ (d & 7);
      gload_lds16(VtG + (long)hk * (128 * kT) + (long)d * kT + kn * 64 + 8 * lc,
                  Vt + (w * 4 + it) * 512);
    }
    __syncthreads();  // (2) staging complete

    // S = Q K^T  (kf shared across both m-tiles)
    floatx4 S[2][4];
#pragma unroll
    for (int mt = 0; mt < 2; ++mt)
#pragma unroll
      for (int ct = 0; ct < 4; ++ct) S[mt][ct] = zero;
#pragma unroll
    for (int ks = 0; ks < 4; ++ks) {
#pragma unroll
      for (int ct = 0; ct < 4; ++ct) {
        int row = 16 * ct + n;
        short8 kf = *(const short8*)(Ks + row * 128 + ((4 * ks + quad) ^ n) * 8);
        S[0][ct] = __builtin_amdgcn_mfma_f32_16x16x32_bf16(qf[0][ks], kf, S[0][ct], 0, 0, 0);
        S[1][ct] = __builtin_amdgcn_mfma_f32_16x16x32_bf16(qf[1][ks], kf, S[1][ct], 0, 0, 0);
      }
    }
    // no barrier: Ps is a separate buffer, each wave's rows are private

    // p = exp(s*scale); write Ps (128 rows x 64 cols, row-swizzled)
    const bool needmask = (kn >= 2 * bm);
    const int jbase = (kn - 2 * bm) * 64;
    const int hi = n >> 3, lo = n & 7;
#pragma unroll
    for (int mt = 0; mt < 2; ++mt) {
#pragma unroll
      for (int r = 0; r < 4; ++r) {
        int prow = 32 * w + 16 * mt + quad * 4 + r;
        float p0 = __expf(S[mt][0][r] * kScale);
        float p1 = __expf(S[mt][1][r] * kScale);
        float p2 = __expf(S[mt][2][r] * kScale);
        float p3 = __expf(S[mt][3][r] * kScale);
        if (needmask) {
          if (jbase + n > prow) p0 = 0.f;
          if (jbase + 16 + n > prow) p1 = 0.f;
          if (jbase + 32 + n > prow) p2 = 0.f;
          if (jbase + 48 + n > prow) p3 = 0.f;
        }
        int sw = prow & 7;
        Ps[prow * 64 + (((0 + hi) ^ sw) << 3) + lo] = f2bf(p0);
        Ps[prow * 64 + (((2 + hi) ^ sw) << 3) + lo] = f2bf(p1);
        Ps[prow * 64 + (((4 + hi) ^ sw) << 3) + lo] = f2bf(p2);
        Ps[prow * 64 + (((6 + hi) ^ sw) << 3) + lo] = f2bf(p3);
      }
    }
    __asm__ volatile("s_waitcnt lgkmcnt(0)" ::: "memory");  // own-wave Ps visible

    // O += P V ; Ol += P @ ones  (vf shared across both m-tiles)
#pragma unroll
    for (int ks = 0; ks < 2; ++ks) {
      int r0 = 32 * w + n, r1 = 32 * w + 16 + n;
      short8 pf0 = *(const short8*)(Ps + r0 * 64 + (((4 * ks + quad) ^ (r0 & 7)) << 3));
      short8 pf1 = *(const short8*)(Ps + r1 * 64 + (((4 * ks + quad) ^ (r1 & 7)) << 3));
      Ol[0] = __builtin_amdgcn_mfma_f32_16x16x32_bf16(pf0, lfrag, Ol[0], 0, 0, 0);
      Ol[1] = __builtin_amdgcn_mfma_f32_16x16x32_bf16(pf1, lfrag, Ol[1], 0, 0, 0);
#pragma unroll
      for (int dt = 0; dt < 8; ++dt) {
        int d = 16 * dt + n;
        short8 vf = *(const short8*)(Vt + d * 64 + (((4 * ks + quad) ^ (d & 7)) << 3));
        O[0][dt] = __builtin_amdgcn_mfma_f32_16x16x32_bf16(pf0, vf, O[0][dt], 0, 0, 0);
        O[1][dt] = __builtin_amdgcn_mfma_f32_16x16x32_bf16(pf1, vf, O[1][dt], 0, 0, 0);
      }
    }
  }

  // epilogue: l broadcast, normalize, gate, store bf16
#pragma unroll
  for (int mt = 0; mt < 2; ++mt) {
#pragma unroll
    for (int r = 0; r < 4; ++r) {
      float l = __shfl(Ol[mt][r], quad << 4, 64);
      float inv = 1.0f / l;
      int row = q0 + 32 * w + 16 * mt + quad * 4 + r;
#pragma unroll
      for (int dt = 0; dt < 8; ++dt) {
        int col = 16 * dt + n;
        float gte = qkvf[(long)row * kNqkv + 256 * h + 128 + col];
        og[(long)row * kHid + 128 * h + col] = f2bf(O[mt][dt][r] * inv * gte);
      }
    }
  }
}

extern "C" void kernel_launch(void* const* d_in, const int* in_sizes, int n_in,
                              void* d_out, int out_size, void* d_ws, size_t ws_size,
                              hipStream_t stream) {
  (void)in_sizes; (void)n_in; (void)out_size; (void)ws_size;
  const float* hs   = (const float*)d_in[0];
  const float* cosb = (const float*)d_in[1];
  const float* sinb = (const float*)d_in[2];
  const float* wqkv = (const float*)d_in[3];
  const float* wo   = (const float*)d_in[4];
  const float* qw   = (const float*)d_in[5];
  const float* kw   = (const float*)d_in[6];
  float* out = (float*)d_out;

  char* ws = (char*)d_ws;
  float* qkv = (float*)ws;                                    // 75.5 MB fp32
  unsigned short* hsb = (unsigned short*)(ws + 75497472);     // 16.8 MB (aliases og)
  unsigned short* og  = hsb;                                  // written after hsb dead
  unsigned short* wt  = (unsigned short*)(ws + 92274688);     // 18.9 MB shared
  unsigned short* VtG = wt;  // aliases dead w_qkv^T during flash (w_o^T written after)

  cvt_bf16<<<dim3(8192), 256, 0, stream>>>(hs, hsb, (long)kT * kHid);
  transpose_cvt<<<dim3(kNqkv / 32, kHid / 32), 256, 0, stream>>>(wqkv, wt, kHid, kNqkv);
  gemm256<<<dim3(kT / 256, kNqkv / 256), 512, 0, stream>>>(hsb, wt, qkv, kT, kNqkv, kHid);
  vt_transpose<<<dim3(kT / 32, 8), 256, 0, stream>>>(qkv, VtG);
  norm_rope_cvt<<<dim3(2304), 256, 0, stream>>>(qkv, cosb, sinb, qw, kw);
  flash_attn_mfma<<<dim3(kT / 128 * kH), 256, 0, stream>>>((const unsigned short*)qkv, qkv, VtG, og);
  transpose_cvt<<<dim3(kHid / 32, kHid / 32), 256, 0, stream>>>(wo, wt, kHid, kHid);
  gemm_bf16<<<dim3(kT / 128, kHid / 128), 256, 0, stream>>>(og, wt, out, kT, kHid, kHid);
}

// Round 13
// 522.002 us; speedup vs baseline: 1.0911x; 1.0911x over previous
//
#include <hip/hip_runtime.h>
#include <hip/hip_bf16.h>
#include <math.h>

// Qwen3.5 attention block, bf16-MFMA everywhere.
// cvt(hs), transpose_cvt(w_qkv) -> gemm256 v2 (QKV, coalesced staging) ->
// vt_transpose -> norm_rope_cvt (wave-parallel) ->
// flash_attn_mfma v10 -> transpose_cvt(w_o) -> gemm_bf16 (out, 128^2).

namespace {
constexpr int kT   = 4096;
constexpr int kHid = 2048;
constexpr int kH   = 16;
constexpr int kHkv = 2;
constexpr int kD   = 128;
constexpr int kNqkv = (2 * kH + 2 * kHkv) * kD;  // 4608 floats per row
constexpr int kQsz  = 2 * kH * kD;               // 4096
constexpr int kRowU = kNqkv * 2;                 // 9216 ushorts per row
constexpr float kEps = 1e-6f;
constexpr float kScale = 0.08838834764831845f;   // 128^-0.5
}

typedef __attribute__((ext_vector_type(8))) short short8;
typedef __attribute__((ext_vector_type(4))) float floatx4;

__device__ inline unsigned short f2bf(float x) {
  unsigned u = __float_as_uint(x);
  u = (u + 0x7fffu + ((u >> 16) & 1u)) >> 16;
  return (unsigned short)u;
}

__device__ inline void gload_lds16(const void* g, void* l) {
  typedef const __attribute__((address_space(1))) unsigned GQ;
  typedef __attribute__((address_space(3))) unsigned LQ;
  __builtin_amdgcn_global_load_lds((GQ*)g, (LQ*)l, 16, 0, 0);
}

// ---- fp32 -> bf16 elementwise ----
__global__ __launch_bounds__(256)
void cvt_bf16(const float* __restrict__ in, unsigned short* __restrict__ out,
              long nelem) {
  long i = ((long)blockIdx.x * 256 + threadIdx.x) * 4;
  if (i >= nelem) return;
  float4 v = *(const float4*)(in + i);
  unsigned long long p = (unsigned long long)f2bf(v.x) |
                         ((unsigned long long)f2bf(v.y) << 16) |
                         ((unsigned long long)f2bf(v.z) << 32) |
                         ((unsigned long long)f2bf(v.w) << 48);
  *(unsigned long long*)(out + i) = p;
}

// ---- fp32 [R][C] -> bf16 [C][R] tiled transpose ----
__global__ __launch_bounds__(256)
void transpose_cvt(const float* __restrict__ in, unsigned short* __restrict__ out,
                   int R, int C) {
  __shared__ float t[32][33];
  const int bx = blockIdx.x * 32;
  const int by = blockIdx.y * 32;
  const int x = threadIdx.x & 31, y = threadIdx.x >> 5;
#pragma unroll
  for (int j = 0; j < 4; ++j)
    t[y * 4 + j][x] = in[(long)(by + y * 4 + j) * C + bx + x];
  __syncthreads();
#pragma unroll
  for (int j = 0; j < 4; ++j)
    out[(long)(bx + y * 4 + j) * R + by + x] = f2bf(t[x][y * 4 + j]);
}

// ---- V^T pre-transpose: qkv fp32 V (rows t, 256 cols) -> VtG bf16 [256][T] ----
__global__ __launch_bounds__(256)
void vt_transpose(const float* __restrict__ qkv, unsigned short* __restrict__ VtG) {
  __shared__ float t[32][33];
  const int t0 = blockIdx.x * 32;
  const int c0 = blockIdx.y * 32;
  const int x = threadIdx.x & 31, y = threadIdx.x >> 5;
#pragma unroll
  for (int j = 0; j < 4; ++j)
    t[y * 4 + j][x] = qkv[(long)(t0 + y * 4 + j) * kNqkv + 4352 + c0 + x];
  __syncthreads();
#pragma unroll
  for (int j = 0; j < 4; ++j)
    VtG[(long)(c0 + y * 4 + j) * kT + t0 + x] = f2bf(t[x][y * 4 + j]);
}

// ---- gemm256 v2: C[M,N] fp32 = A[M,K]bf16 @ Bt[N,K]bf16^T. ----
// BM=BN=256, BK=64 in 2 K-halves; 512 thr = 8 waves (2m x 4n), acc[8][4].
// LDS per (parity,khalf): 256 rows x 4 chunks of 16B, unit = 4r + c.
// v2 FIX (v1: 64 lanes read 64 rows at 4KB stride = 64 scattered txns/inst):
// staging r=ci>>2, c=ci&3 -> 4 lanes cover one row's 64B, COALESCED
// (16x64B txns/inst). Source chunk XOR-swizzled cg = c ^ ((r>>1)&3);
// fragment read unit = 4*row + (quad ^ ((row>>1)&3)) -> 16B-unit mod 8 =
// 4(r&1) + quad^s(r) spreads 2 lanes/bank-group = conflict-free (m136).
// Schedule unchanged: 4 phases/tile, counted vmcnt(4) mid+boundary,
// pipeline never drains mid-loop, setprio around MFMA clusters.
__global__ __launch_bounds__(512)
void gemm256(const unsigned short* __restrict__ A,
             const unsigned short* __restrict__ Bt, float* __restrict__ C,
             int M, int N, int K) {
  __shared__ __align__(16) unsigned short As[2][2][8192];  // [parity][khalf]
  __shared__ __align__(16) unsigned short Bs[2][2][8192];
  const int tid = threadIdx.x;
  const int lane = tid & 63;
  const int w = tid >> 6;            // 0..7
  const int wm = w >> 2, wn = w & 3; // wave tile: rows wm*128, cols wn*64
  const int n16 = lane & 15, quad = lane >> 4;
  const long bm = (long)blockIdx.x * 256, bn = (long)blockIdx.y * 256;
  const int NT = K >> 6;

  floatx4 acc[8][4];
  floatx4 zero = {0.f, 0.f, 0.f, 0.f};
#pragma unroll
  for (int mf = 0; mf < 8; ++mf)
#pragma unroll
    for (int nf = 0; nf < 4; ++nf) acc[mf][nf] = zero;

  // stage one k-half (256 rows x 32 k): coalesced, source-swizzled
  auto stageA = [&](int p, int kh, int kt) {
#pragma unroll
    for (int it = 0; it < 2; ++it) {
      int ci = it * 512 + tid;            // 0..1023
      int r = ci >> 2, c = ci & 3;        // row, chunk slot
      int cg = c ^ ((r >> 1) & 3);        // swizzled source chunk
      gload_lds16(A + (bm + r) * (long)K + kt * 64 + kh * 32 + cg * 8,
                  &As[p][kh][(it * 512 + w * 64) * 8]);
    }
  };
  auto stageB = [&](int p, int kh, int kt) {
#pragma unroll
    for (int it = 0; it < 2; ++it) {
      int ci = it * 512 + tid;
      int r = ci >> 2, c = ci & 3;
      int cg = c ^ ((r >> 1) & 3);
      gload_lds16(Bt + (bn + r) * (long)K + kt * 64 + kh * 32 + cg * 8,
                  &Bs[p][kh][(it * 512 + w * 64) * 8]);
    }
  };
  // fragment read: global chunk q of row -> unit 4*row + (q ^ ((row>>1)&3))
#define AFRAG(p, kh, row) \
  (*(const short8*)(&As[p][kh][(4 * (row) + (quad ^ (((row) >> 1) & 3))) * 8]))
#define BFRAG(p, kh, row) \
  (*(const short8*)(&Bs[p][kh][(4 * (row) + (quad ^ (((row) >> 1) & 3))) * 8]))

  // prologue: tile 0 fully staged
  stageA(0, 0, 0); stageB(0, 0, 0); stageA(0, 1, 0); stageB(0, 1, 0);
  __asm__ volatile("s_waitcnt vmcnt(0)" ::: "memory");
  __builtin_amdgcn_s_barrier();
  __builtin_amdgcn_sched_barrier(0);

  for (int t = 0; t < NT; ++t) {
    const int p = t & 1, ps = p ^ 1;
    const bool pre = (t + 1 < NT);
    short8 af[8], bf[2];

    // ---- phase 0: ks=0, nf 0-1 ----
    if (pre) stageA(ps, 0, t + 1);
#pragma unroll
    for (int mf = 0; mf < 8; ++mf)
      af[mf] = AFRAG(p, 0, wm * 128 + mf * 16 + n16);
#pragma unroll
    for (int nf = 0; nf < 2; ++nf)
      bf[nf] = BFRAG(p, 0, wn * 64 + nf * 16 + n16);
    __builtin_amdgcn_s_setprio(1);
#pragma unroll
    for (int mf = 0; mf < 8; ++mf)
#pragma unroll
      for (int nf = 0; nf < 2; ++nf)
        acc[mf][nf] = __builtin_amdgcn_mfma_f32_16x16x32_bf16(af[mf], bf[nf], acc[mf][nf], 0, 0, 0);
    __builtin_amdgcn_s_setprio(0);

    // ---- phase 1: ks=0, nf 2-3 (af reused) ----
    if (pre) stageB(ps, 0, t + 1);
#pragma unroll
    for (int nf = 0; nf < 2; ++nf)
      bf[nf] = BFRAG(p, 0, wn * 64 + (nf + 2) * 16 + n16);
    __builtin_amdgcn_s_setprio(1);
#pragma unroll
    for (int mf = 0; mf < 8; ++mf)
#pragma unroll
      for (int nf = 0; nf < 2; ++nf)
        acc[mf][nf + 2] = __builtin_amdgcn_mfma_f32_16x16x32_bf16(af[mf], bf[nf], acc[mf][nf + 2], 0, 0, 0);
    __builtin_amdgcn_s_setprio(0);

    // ---- mid-tile: this tile's kh1 landed (issued 2 phases ago) ----
    if (pre) { __asm__ volatile("s_waitcnt vmcnt(4)" ::: "memory"); }
    else     { __asm__ volatile("s_waitcnt vmcnt(0)" ::: "memory"); }
    __builtin_amdgcn_s_barrier();
    __builtin_amdgcn_sched_barrier(0);

    // ---- phase 2: ks=1, nf 0-1 ----
    if (pre) stageA(ps, 1, t + 1);
#pragma unroll
    for (int mf = 0; mf < 8; ++mf)
      af[mf] = AFRAG(p, 1, wm * 128 + mf * 16 + n16);
#pragma unroll
    for (int nf = 0; nf < 2; ++nf)
      bf[nf] = BFRAG(p, 1, wn * 64 + nf * 16 + n16);
    __builtin_amdgcn_s_setprio(1);
#pragma unroll
    for (int mf = 0; mf < 8; ++mf)
#pragma unroll
      for (int nf = 0; nf < 2; ++nf)
        acc[mf][nf] = __builtin_amdgcn_mfma_f32_16x16x32_bf16(af[mf], bf[nf], acc[mf][nf], 0, 0, 0);
    __builtin_amdgcn_s_setprio(0);

    // ---- phase 3: ks=1, nf 2-3 ----
    if (pre) stageB(ps, 1, t + 1);
#pragma unroll
    for (int nf = 0; nf < 2; ++nf)
      bf[nf] = BFRAG(p, 1, wn * 64 + (nf + 2) * 16 + n16);
    __builtin_amdgcn_s_setprio(1);
#pragma unroll
    for (int mf = 0; mf < 8; ++mf)
#pragma unroll
      for (int nf = 0; nf < 2; ++nf)
        acc[mf][nf + 2] = __builtin_amdgcn_mfma_f32_16x16x32_bf16(af[mf], bf[nf], acc[mf][nf + 2], 0, 0, 0);
    __builtin_amdgcn_s_setprio(0);

    // ---- boundary: next tile's kh0 landed; its kh1 stays in flight ----
    if (pre) {
      __asm__ volatile("s_waitcnt vmcnt(4)" ::: "memory");
      __builtin_amdgcn_s_barrier();
      __builtin_amdgcn_sched_barrier(0);
    }
  }
#undef AFRAG
#undef BFRAG

  // epilogue
#pragma unroll
  for (int mf = 0; mf < 8; ++mf)
#pragma unroll
    for (int nf = 0; nf < 4; ++nf)
#pragma unroll
      for (int r = 0; r < 4; ++r)
        C[(bm + wm * 128 + mf * 16 + quad * 4 + r) * (long)N + bn + wn * 64 + nf * 16 + n16] =
            acc[mf][nf][r];
}

// ---- C[M,N] fp32 = A[M,K]bf16 @ Bt[N,K]bf16^T. 128x128 tile, BK=64. ----
__global__ __launch_bounds__(256)
void gemm_bf16(const unsigned short* __restrict__ A,
               const unsigned short* __restrict__ Bt, float* __restrict__ C,
               int M, int N, int K) {
  __shared__ __align__(16) unsigned short As[128 * 64];
  __shared__ __align__(16) unsigned short Bs[128 * 64];
  const int tid = threadIdx.x;
  const int lane = tid & 63;
  const int w = tid >> 6;
  const int wr = w >> 1, wc = w & 1;
  const int n = lane & 15;
  const int quad = lane >> 4;
  const long bm = (long)blockIdx.x * 128, bn = (long)blockIdx.y * 128;

  floatx4 acc[4][4];
  floatx4 zero = {0.f, 0.f, 0.f, 0.f};
#pragma unroll
  for (int a = 0; a < 4; ++a)
#pragma unroll
    for (int b = 0; b < 4; ++b) acc[a][b] = zero;

  for (int k0 = 0; k0 < K; k0 += 64) {
    __syncthreads();
#pragma unroll
    for (int it = 0; it < 4; ++it) {
      int ci = it * 256 + tid;            // 16B chunk id 0..1023
      int r = ci >> 3, c = ci & 7;
      int cg = c ^ (r & 7);               // global chunk for this slot
      gload_lds16(A + (bm + r) * (long)K + k0 + cg * 8, As + (it * 256 + w * 64) * 8);
      gload_lds16(Bt + (bn + r) * (long)K + k0 + cg * 8, Bs + (it * 256 + w * 64) * 8);
    }
    __syncthreads();

#pragma unroll
    for (int ks = 0; ks < 2; ++ks) {
      short8 af[4], bf[4];
#pragma unroll
      for (int a = 0; a < 4; ++a) {
        int m = wr * 64 + a * 16 + n;
        af[a] = *(const short8*)(As + m * 64 + ((4 * ks + quad) ^ (m & 7)) * 8);
      }
#pragma unroll
      for (int b = 0; b < 4; ++b) {
        int nn = wc * 64 + b * 16 + n;
        bf[b] = *(const short8*)(Bs + nn * 64 + ((4 * ks + quad) ^ (nn & 7)) * 8);
      }
#pragma unroll
      for (int a = 0; a < 4; ++a)
#pragma unroll
        for (int b = 0; b < 4; ++b)
          acc[a][b] = __builtin_amdgcn_mfma_f32_16x16x32_bf16(af[a], bf[b], acc[a][b], 0, 0, 0);
    }
  }
#pragma unroll
  for (int a = 0; a < 4; ++a)
#pragma unroll
    for (int b = 0; b < 4; ++b)
#pragma unroll
      for (int r = 0; r < 4; ++r)
        C[(bm + wr * 64 + a * 16 + quad * 4 + r) * (long)N + bn + wc * 64 + b * 16 + n] =
            acc[a][b][r];
}

// ------- RMSNorm + RoPE + bf16 pack (q,k), wave-parallel, barrier-free -------
__global__ __launch_bounds__(256)
void norm_rope_cvt(float* qkv, const float* __restrict__ cosb,
                   const float* __restrict__ sinb, const float* __restrict__ qw,
                   const float* __restrict__ kw) {
  unsigned short* qkvu = (unsigned short*)qkv;
  const int lane = threadIdx.x & 63;
  const int wslot = blockIdx.x * 4 + (threadIdx.x >> 6);
  const int nslots = gridDim.x * 4;
  for (int task = wslot; task < kT * 18; task += nslots) {
    const int t = task / 18;
    const int h = task % 18;
    const bool isq = (h < kH);
    const long base = (long)t * kNqkv + (isq ? h * 2 * kD : kQsz + (h - kH) * kD);
    float xlo = qkv[base + lane];
    float xhi = qkv[base + 64 + lane];
    float v = xlo * xlo + xhi * xhi;
#pragma unroll
    for (int off = 1; off < 64; off <<= 1) v += __shfl_xor(v, off, 64);
    float rms = rsqrtf(v * (1.0f / kD) + kEps);
    const float* wv = isq ? qw : kw;
    float nlo = xlo * rms * wv[lane];
    float nhi = xhi * rms * wv[64 + lane];
    float clo = cosb[t * kD + lane], chi = cosb[t * kD + 64 + lane];
    float slo = sinb[t * kD + lane], shi = sinb[t * kD + 64 + lane];
    float rlo = nlo * clo - nhi * slo;   // rot(lo) = -x[l+64]
    float rhi = nhi * chi + nlo * shi;   // rot(hi) = +x[l]
    if (isq) {
      float glo = qkv[base + kD + lane];
      float ghi = qkv[base + kD + 64 + lane];
      qkv[base + kD + lane] = 1.0f / (1.0f + __expf(-glo));
      qkv[base + kD + 64 + lane] = 1.0f / (1.0f + __expf(-ghi));
      qkvu[(long)t * kRowU + 512 * h + lane] = f2bf(rlo);
      qkvu[(long)t * kRowU + 512 * h + 64 + lane] = f2bf(rhi);
    } else {
      qkvu[(long)t * kRowU + 8192 + 256 * (h - kH) + lane] = f2bf(rlo);
      qkvu[(long)t * kRowU + 8192 + 256 * (h - kH) + 64 + lane] = f2bf(rhi);
    }
  }
}

// ---------------- bf16 MFMA flash attention v10 (best: 166.7us) -------------
// v3 structure + dedicated Ps buffer (barrier (3) removed; 2 barriers/tile).
__global__ __launch_bounds__(256)
void flash_attn_mfma(const unsigned short* qkvu, const float* qkvf,
                     const unsigned short* VtG, unsigned short* __restrict__ og) {
  __shared__ __align__(16) unsigned short Ks[64 * 128];  // K tile (swizzled)
  __shared__ __align__(16) unsigned short Vt[128 * 64];  // V^T tile (swizzled)
  __shared__ __align__(16) unsigned short Ps[128 * 64];  // P tile (row-swizzled)

  const int tid = threadIdx.x;
  const int lane = tid & 63;
  const int w = tid >> 6;
  const int n = lane & 15;
  const int quad = lane >> 4;
  const int g = blockIdx.x;
  const int h = g & 15;
  const int bm = 31 - (g >> 4);   // heavy-first
  const int hk = h >> 3;
  const int q0 = bm * 128;

  short8 qf[2][4];
#pragma unroll
  for (int mt = 0; mt < 2; ++mt) {
    const unsigned short* qrow =
        qkvu + (long)(q0 + 32 * w + 16 * mt + n) * kRowU + 512 * h;
#pragma unroll
    for (int ks = 0; ks < 4; ++ks)
      qf[mt][ks] = *(const short8*)(qrow + 32 * ks + 8 * quad);
  }
  short8 lfrag;  // B-frag: col 0 = ones -> row-sum accumulator
  {
    short o = (n == 0) ? (short)0x3F80 : (short)0;
    lfrag = (short8){o, o, o, o, o, o, o, o};
  }

  floatx4 O[2][8];
  floatx4 Ol[2];
  floatx4 zero = {0.f, 0.f, 0.f, 0.f};
#pragma unroll
  for (int mt = 0; mt < 2; ++mt) {
    Ol[mt] = zero;
#pragma unroll
    for (int dt = 0; dt < 8; ++dt) O[mt][dt] = zero;
  }

  const int kn_end = 2 * bm + 1;
  for (int kn = 0; kn <= kn_end; ++kn) {
    __syncthreads();  // (1) prev QK+PV reads done before restage
    // stage K: 64 rows x 128 d, chunk swizzle c ^ (r&15)
#pragma unroll
    for (int it = 0; it < 4; ++it) {
      int pc = (w * 4 + it) * 64 + lane;
      int r = pc >> 4, c = pc & 15;
      int lc = c ^ (r & 15);
      gload_lds16(qkvu + (long)(kn * 64 + r) * kRowU + 8192 + 256 * hk + 8 * lc,
                  Ks + (w * 4 + it) * 512);
    }
    // stage V^T: 128 rows (d) x 64 keys, chunk swizzle c ^ (d&7)
#pragma unroll
    for (int it = 0; it < 4; ++it) {
      int pc = (w * 4 + it) * 64 + lane;
      int d = pc >> 3, c = pc & 7;
      int lc = c ^ (d & 7);
      gload_lds16(VtG + (long)hk * (128 * kT) + (long)d * kT + kn * 64 + 8 * lc,
                  Vt + (w * 4 + it) * 512);
    }
    __syncthreads();  // (2) staging complete

    // S = Q K^T  (kf shared across both m-tiles)
    floatx4 S[2][4];
#pragma unroll
    for (int mt = 0; mt < 2; ++mt)
#pragma unroll
      for (int ct = 0; ct < 4; ++ct) S[mt][ct] = zero;
#pragma unroll
    for (int ks = 0; ks < 4; ++ks) {
#pragma unroll
      for (int ct = 0; ct < 4; ++ct) {
        int row = 16 * ct + n;
        short8 kf = *(const short8*)(Ks + row * 128 + ((4 * ks + quad) ^ n) * 8);
        S[0][ct] = __builtin_amdgcn_mfma_f32_16x16x32_bf16(qf[0][ks], kf, S[0][ct], 0, 0, 0);
        S[1][ct] = __builtin_amdgcn_mfma_f32_16x16x32_bf16(qf[1][ks], kf, S[1][ct], 0, 0, 0);
      }
    }
    // no barrier: Ps is a separate buffer, each wave's rows are private

    // p = exp(s*scale); write Ps (128 rows x 64 cols, row-swizzled)
    const bool needmask = (kn >= 2 * bm);
    const int jbase = (kn - 2 * bm) * 64;
    const int hi = n >> 3, lo = n & 7;
#pragma unroll
    for (int mt = 0; mt < 2; ++mt) {
#pragma unroll
      for (int r = 0; r < 4; ++r) {
        int prow = 32 * w + 16 * mt + quad * 4 + r;
        float p0 = __expf(S[mt][0][r] * kScale);
        float p1 = __expf(S[mt][1][r] * kScale);
        float p2 = __expf(S[mt][2][r] * kScale);
        float p3 = __expf(S[mt][3][r] * kScale);
        if (needmask) {
          if (jbase + n > prow) p0 = 0.f;
          if (jbase + 16 + n > prow) p1 = 0.f;
          if (jbase + 32 + n > prow) p2 = 0.f;
          if (jbase + 48 + n > prow) p3 = 0.f;
        }
        int sw = prow & 7;
        Ps[prow * 64 + (((0 + hi) ^ sw) << 3) + lo] = f2bf(p0);
        Ps[prow * 64 + (((2 + hi) ^ sw) << 3) + lo] = f2bf(p1);
        Ps[prow * 64 + (((4 + hi) ^ sw) << 3) + lo] = f2bf(p2);
        Ps[prow * 64 + (((6 + hi) ^ sw) << 3) + lo] = f2bf(p3);
      }
    }
    __asm__ volatile("s_waitcnt lgkmcnt(0)" ::: "memory");  // own-wave Ps visible

    // O += P V ; Ol += P @ ones  (vf shared across both m-tiles)
#pragma unroll
    for (int ks = 0; ks < 2; ++ks) {
      int r0 = 32 * w + n, r1 = 32 * w + 16 + n;
      short8 pf0 = *(const short8*)(Ps + r0 * 64 + (((4 * ks + quad) ^ (r0 & 7)) << 3));
      short8 pf1 = *(const short8*)(Ps + r1 * 64 + (((4 * ks + quad) ^ (r1 & 7)) << 3));
      Ol[0] = __builtin_amdgcn_mfma_f32_16x16x32_bf16(pf0, lfrag, Ol[0], 0, 0, 0);
      Ol[1] = __builtin_amdgcn_mfma_f32_16x16x32_bf16(pf1, lfrag, Ol[1], 0, 0, 0);
#pragma unroll
      for (int dt = 0; dt < 8; ++dt) {
        int d = 16 * dt + n;
        short8 vf = *(const short8*)(Vt + d * 64 + (((4 * ks + quad) ^ (d & 7)) << 3));
        O[0][dt] = __builtin_amdgcn_mfma_f32_16x16x32_bf16(pf0, vf, O[0][dt], 0, 0, 0);
        O[1][dt] = __builtin_amdgcn_mfma_f32_16x16x32_bf16(pf1, vf, O[1][dt], 0, 0, 0);
      }
    }
  }

  // epilogue: l broadcast, normalize, gate, store bf16
#pragma unroll
  for (int mt = 0; mt < 2; ++mt) {
#pragma unroll
    for (int r = 0; r < 4; ++r) {
      float l = __shfl(Ol[mt][r], quad << 4, 64);
      float inv = 1.0f / l;
      int row = q0 + 32 * w + 16 * mt + quad * 4 + r;
#pragma unroll
      for (int dt = 0; dt < 8; ++dt) {
        int col = 16 * dt + n;
        float gte = qkvf[(long)row * kNqkv + 256 * h + 128 + col];
        og[(long)row * kHid + 128 * h + col] = f2bf(O[mt][dt][r] * inv * gte);
      }
    }
  }
}

extern "C" void kernel_launch(void* const* d_in, const int* in_sizes, int n_in,
                              void* d_out, int out_size, void* d_ws, size_t ws_size,
                              hipStream_t stream) {
  (void)in_sizes; (void)n_in; (void)out_size; (void)ws_size;
  const float* hs   = (const float*)d_in[0];
  const float* cosb = (const float*)d_in[1];
  const float* sinb = (const float*)d_in[2];
  const float* wqkv = (const float*)d_in[3];
  const float* wo   = (const float*)d_in[4];
  const float* qw   = (const float*)d_in[5];
  const float* kw   = (const float*)d_in[6];
  float* out = (float*)d_out;

  char* ws = (char*)d_ws;
  float* qkv = (float*)ws;                                    // 75.5 MB fp32
  unsigned short* hsb = (unsigned short*)(ws + 75497472);     // 16.8 MB (aliases og)
  unsigned short* og  = hsb;                                  // written after hsb dead
  unsigned short* wt  = (unsigned short*)(ws + 92274688);     // 18.9 MB shared
  unsigned short* VtG = wt;  // aliases dead w_qkv^T during flash (w_o^T written after)

  cvt_bf16<<<dim3(8192), 256, 0, stream>>>(hs, hsb, (long)kT * kHid);
  transpose_cvt<<<dim3(kNqkv / 32, kHid / 32), 256, 0, stream>>>(wqkv, wt, kHid, kNqkv);
  gemm256<<<dim3(kT / 256, kNqkv / 256), 512, 0, stream>>>(hsb, wt, qkv, kT, kNqkv, kHid);
  vt_transpose<<<dim3(kT / 32, 8), 256, 0, stream>>>(qkv, VtG);
  norm_rope_cvt<<<dim3(2304), 256, 0, stream>>>(qkv, cosb, sinb, qw, kw);
  flash_attn_mfma<<<dim3(kT / 128 * kH), 256, 0, stream>>>((const unsigned short*)qkv, qkv, VtG, og);
  transpose_cvt<<<dim3(kHid / 32, kHid / 32), 256, 0, stream>>>(wo, wt, kHid, kHid);
  gemm_bf16<<<dim3(kT / 128, kHid / 128), 256, 0, stream>>>(og, wt, out, kT, kHid, kHid);
}

// Round 14
// 497.063 us; speedup vs baseline: 1.1458x; 1.0502x over previous
//
#include <hip/hip_runtime.h>
#include <hip/hip_bf16.h>
#include <math.h>

// Qwen3.5 attention block, bf16-MFMA everywhere.
// cvt(hs), transpose_cvt(w_qkv) -> gemm_bf16(QKV, 128^2, XCD swizzle) ->
// vt_transpose -> norm_rope_cvt (wave-parallel) ->
// flash_attn_mfma v10 (exp2 fold) -> transpose_cvt(w_o) -> gemm_bf16(out).
//
// Structural notes (session evidence):
// - 128^2 GEMM tile is grid-optimal for these shapes (QKV grid 32x36=1152
//   blocks, 2.5/CU backfill). 256^2 tiles -> 288-block grid at 1 blk/CU
//   (128KB LDS) -> makespan 2x per-tile time (56% util): refuted (r12/r13).
// - flash: per-tile cost saturates at ~2.5us/tile/CU regardless of TLP
//   (2 vs 3 vs 6 blocks/CU all equal); barrier-removal via dedicated Ps
//   was the only win. Split-K linear-combine: flash -4us but +10us combine.

namespace {
constexpr int kT   = 4096;
constexpr int kHid = 2048;
constexpr int kH   = 16;
constexpr int kHkv = 2;
constexpr int kD   = 128;
constexpr int kNqkv = (2 * kH + 2 * kHkv) * kD;  // 4608 floats per row
constexpr int kQsz  = 2 * kH * kD;               // 4096
constexpr int kRowU = kNqkv * 2;                 // 9216 ushorts per row
constexpr float kEps = 1e-6f;
constexpr float kScaleLog2 = 0.12751742729928068f;  // 128^-0.5 * log2(e)
}

typedef __attribute__((ext_vector_type(8))) short short8;
typedef __attribute__((ext_vector_type(4))) float floatx4;

__device__ inline unsigned short f2bf(float x) {
  unsigned u = __float_as_uint(x);
  u = (u + 0x7fffu + ((u >> 16) & 1u)) >> 16;
  return (unsigned short)u;
}

__device__ inline void gload_lds16(const void* g, void* l) {
  typedef const __attribute__((address_space(1))) unsigned GQ;
  typedef __attribute__((address_space(3))) unsigned LQ;
  __builtin_amdgcn_global_load_lds((GQ*)g, (LQ*)l, 16, 0, 0);
}

// ---- fp32 -> bf16 elementwise ----
__global__ __launch_bounds__(256)
void cvt_bf16(const float* __restrict__ in, unsigned short* __restrict__ out,
              long nelem) {
  long i = ((long)blockIdx.x * 256 + threadIdx.x) * 4;
  if (i >= nelem) return;
  float4 v = *(const float4*)(in + i);
  unsigned long long p = (unsigned long long)f2bf(v.x) |
                         ((unsigned long long)f2bf(v.y) << 16) |
                         ((unsigned long long)f2bf(v.z) << 32) |
                         ((unsigned long long)f2bf(v.w) << 48);
  *(unsigned long long*)(out + i) = p;
}

// ---- fp32 [R][C] -> bf16 [C][R] tiled transpose ----
__global__ __launch_bounds__(256)
void transpose_cvt(const float* __restrict__ in, unsigned short* __restrict__ out,
                   int R, int C) {
  __shared__ float t[32][33];
  const int bx = blockIdx.x * 32;
  const int by = blockIdx.y * 32;
  const int x = threadIdx.x & 31, y = threadIdx.x >> 5;
#pragma unroll
  for (int j = 0; j < 4; ++j)
    t[y * 4 + j][x] = in[(long)(by + y * 4 + j) * C + bx + x];
  __syncthreads();
#pragma unroll
  for (int j = 0; j < 4; ++j)
    out[(long)(bx + y * 4 + j) * R + by + x] = f2bf(t[x][y * 4 + j]);
}

// ---- V^T pre-transpose: qkv fp32 V (rows t, 256 cols) -> VtG bf16 [256][T] ----
__global__ __launch_bounds__(256)
void vt_transpose(const float* __restrict__ qkv, unsigned short* __restrict__ VtG) {
  __shared__ float t[32][33];
  const int t0 = blockIdx.x * 32;
  const int c0 = blockIdx.y * 32;
  const int x = threadIdx.x & 31, y = threadIdx.x >> 5;
#pragma unroll
  for (int j = 0; j < 4; ++j)
    t[y * 4 + j][x] = qkv[(long)(t0 + y * 4 + j) * kNqkv + 4352 + c0 + x];
  __syncthreads();
#pragma unroll
  for (int j = 0; j < 4; ++j)
    VtG[(long)(c0 + y * 4 + j) * kT + t0 + x] = f2bf(t[x][y * 4 + j]);
}

// ---- C[M,N] fp32 = A[M,K]bf16 @ Bt[N,K]bf16^T. 128x128 tile, BK=64. ----
// XCD-band swizzle (null-to-slightly-positive, kept from best build).
__global__ __launch_bounds__(256)
void gemm_bf16(const unsigned short* __restrict__ A,
               const unsigned short* __restrict__ Bt, float* __restrict__ C,
               int M, int N, int K) {
  __shared__ __align__(16) unsigned short As[128 * 64];
  __shared__ __align__(16) unsigned short Bs[128 * 64];
  const int tid = threadIdx.x;
  const int lane = tid & 63;
  const int w = tid >> 6;
  const int wr = w >> 1, wc = w & 1;
  const int n = lane & 15;
  const int quad = lane >> 4;

  int bx = blockIdx.x, by = blockIdx.y;
  const int nbx = gridDim.x, nby = gridDim.y;
  if (nbx == 32 && ((nbx * nby) & 7) == 0) {
    int lin = bx + nbx * by;        // dispatch-linear id (x fastest)
    int xcd = lin & 7, s = lin >> 3;
    bx = 4 * xcd + (s & 3);
    by = s >> 2;
  }
  const long bm = (long)bx * 128, bn = (long)by * 128;

  floatx4 acc[4][4];
  floatx4 zero = {0.f, 0.f, 0.f, 0.f};
#pragma unroll
  for (int a = 0; a < 4; ++a)
#pragma unroll
    for (int b = 0; b < 4; ++b) acc[a][b] = zero;

  for (int k0 = 0; k0 < K; k0 += 64) {
    __syncthreads();
#pragma unroll
    for (int it = 0; it < 4; ++it) {
      int ci = it * 256 + tid;            // 16B chunk id 0..1023
      int r = ci >> 3, c = ci & 7;
      int cg = c ^ (r & 7);               // global chunk for this slot
      gload_lds16(A + (bm + r) * (long)K + k0 + cg * 8, As + (it * 256 + w * 64) * 8);
      gload_lds16(Bt + (bn + r) * (long)K + k0 + cg * 8, Bs + (it * 256 + w * 64) * 8);
    }
    __syncthreads();

#pragma unroll
    for (int ks = 0; ks < 2; ++ks) {
      short8 af[4], bf[4];
#pragma unroll
      for (int a = 0; a < 4; ++a) {
        int m = wr * 64 + a * 16 + n;
        af[a] = *(const short8*)(As + m * 64 + ((4 * ks + quad) ^ (m & 7)) * 8);
      }
#pragma unroll
      for (int b = 0; b < 4; ++b) {
        int nn = wc * 64 + b * 16 + n;
        bf[b] = *(const short8*)(Bs + nn * 64 + ((4 * ks + quad) ^ (nn & 7)) * 8);
      }
#pragma unroll
      for (int a = 0; a < 4; ++a)
#pragma unroll
        for (int b = 0; b < 4; ++b)
          acc[a][b] = __builtin_amdgcn_mfma_f32_16x16x32_bf16(af[a], bf[b], acc[a][b], 0, 0, 0);
    }
  }
#pragma unroll
  for (int a = 0; a < 4; ++a)
#pragma unroll
    for (int b = 0; b < 4; ++b)
#pragma unroll
      for (int r = 0; r < 4; ++r)
        C[(bm + wr * 64 + a * 16 + quad * 4 + r) * (long)N + bn + wc * 64 + b * 16 + n] =
            acc[a][b][r];
}

// ------- RMSNorm + RoPE + bf16 pack (q,k), wave-parallel, barrier-free -------
__global__ __launch_bounds__(256)
void norm_rope_cvt(float* qkv, const float* __restrict__ cosb,
                   const float* __restrict__ sinb, const float* __restrict__ qw,
                   const float* __restrict__ kw) {
  unsigned short* qkvu = (unsigned short*)qkv;
  const int lane = threadIdx.x & 63;
  const int wslot = blockIdx.x * 4 + (threadIdx.x >> 6);
  const int nslots = gridDim.x * 4;
  for (int task = wslot; task < kT * 18; task += nslots) {
    const int t = task / 18;
    const int h = task % 18;
    const bool isq = (h < kH);
    const long base = (long)t * kNqkv + (isq ? h * 2 * kD : kQsz + (h - kH) * kD);
    float xlo = qkv[base + lane];
    float xhi = qkv[base + 64 + lane];
    float v = xlo * xlo + xhi * xhi;
#pragma unroll
    for (int off = 1; off < 64; off <<= 1) v += __shfl_xor(v, off, 64);
    float rms = rsqrtf(v * (1.0f / kD) + kEps);
    const float* wv = isq ? qw : kw;
    float nlo = xlo * rms * wv[lane];
    float nhi = xhi * rms * wv[64 + lane];
    float clo = cosb[t * kD + lane], chi = cosb[t * kD + 64 + lane];
    float slo = sinb[t * kD + lane], shi = sinb[t * kD + 64 + lane];
    float rlo = nlo * clo - nhi * slo;   // rot(lo) = -x[l+64]
    float rhi = nhi * chi + nlo * shi;   // rot(hi) = +x[l]
    if (isq) {
      float glo = qkv[base + kD + lane];
      float ghi = qkv[base + kD + 64 + lane];
      qkv[base + kD + lane] = 1.0f / (1.0f + __expf(-glo));
      qkv[base + kD + 64 + lane] = 1.0f / (1.0f + __expf(-ghi));
      qkvu[(long)t * kRowU + 512 * h + lane] = f2bf(rlo);
      qkvu[(long)t * kRowU + 512 * h + 64 + lane] = f2bf(rhi);
    } else {
      qkvu[(long)t * kRowU + 8192 + 256 * (h - kH) + lane] = f2bf(rlo);
      qkvu[(long)t * kRowU + 8192 + 256 * (h - kH) + 64 + lane] = f2bf(rhi);
    }
  }
}

// ---------------- bf16 MFMA flash attention v10 (best: 165-167us) -----------
// v3 structure + dedicated Ps buffer (barrier (3) removed; 2 barriers/tile).
// exp2 fold: p = exp2(S * scale*log2e) saves one v_mul per element.
__global__ __launch_bounds__(256)
void flash_attn_mfma(const unsigned short* qkvu, const float* qkvf,
                     const unsigned short* VtG, unsigned short* __restrict__ og) {
  __shared__ __align__(16) unsigned short Ks[64 * 128];  // K tile (swizzled)
  __shared__ __align__(16) unsigned short Vt[128 * 64];  // V^T tile (swizzled)
  __shared__ __align__(16) unsigned short Ps[128 * 64];  // P tile (row-swizzled)

  const int tid = threadIdx.x;
  const int lane = tid & 63;
  const int w = tid >> 6;
  const int n = lane & 15;
  const int quad = lane >> 4;
  const int g = blockIdx.x;
  const int h = g & 15;
  const int bm = 31 - (g >> 4);   // heavy-first
  const int hk = h >> 3;
  const int q0 = bm * 128;

  short8 qf[2][4];
#pragma unroll
  for (int mt = 0; mt < 2; ++mt) {
    const unsigned short* qrow =
        qkvu + (long)(q0 + 32 * w + 16 * mt + n) * kRowU + 512 * h;
#pragma unroll
    for (int ks = 0; ks < 4; ++ks)
      qf[mt][ks] = *(const short8*)(qrow + 32 * ks + 8 * quad);
  }
  short8 lfrag;  // B-frag: col 0 = ones -> row-sum accumulator
  {
    short o = (n == 0) ? (short)0x3F80 : (short)0;
    lfrag = (short8){o, o, o, o, o, o, o, o};
  }

  floatx4 O[2][8];
  floatx4 Ol[2];
  floatx4 zero = {0.f, 0.f, 0.f, 0.f};
#pragma unroll
  for (int mt = 0; mt < 2; ++mt) {
    Ol[mt] = zero;
#pragma unroll
    for (int dt = 0; dt < 8; ++dt) O[mt][dt] = zero;
  }

  const int kn_end = 2 * bm + 1;
  for (int kn = 0; kn <= kn_end; ++kn) {
    __syncthreads();  // (1) prev QK+PV reads done before restage
    // stage K: 64 rows x 128 d, chunk swizzle c ^ (r&15)
#pragma unroll
    for (int it = 0; it < 4; ++it) {
      int pc = (w * 4 + it) * 64 + lane;
      int r = pc >> 4, c = pc & 15;
      int lc = c ^ (r & 15);
      gload_lds16(qkvu + (long)(kn * 64 + r) * kRowU + 8192 + 256 * hk + 8 * lc,
                  Ks + (w * 4 + it) * 512);
    }
    // stage V^T: 128 rows (d) x 64 keys, chunk swizzle c ^ (d&7)
#pragma unroll
    for (int it = 0; it < 4; ++it) {
      int pc = (w * 4 + it) * 64 + lane;
      int d = pc >> 3, c = pc & 7;
      int lc = c ^ (d & 7);
      gload_lds16(VtG + (long)hk * (128 * kT) + (long)d * kT + kn * 64 + 8 * lc,
                  Vt + (w * 4 + it) * 512);
    }
    __syncthreads();  // (2) staging complete

    // S = Q K^T  (kf shared across both m-tiles)
    floatx4 S[2][4];
#pragma unroll
    for (int mt = 0; mt < 2; ++mt)
#pragma unroll
      for (int ct = 0; ct < 4; ++ct) S[mt][ct] = zero;
#pragma unroll
    for (int ks = 0; ks < 4; ++ks) {
#pragma unroll
      for (int ct = 0; ct < 4; ++ct) {
        int row = 16 * ct + n;
        short8 kf = *(const short8*)(Ks + row * 128 + ((4 * ks + quad) ^ n) * 8);
        S[0][ct] = __builtin_amdgcn_mfma_f32_16x16x32_bf16(qf[0][ks], kf, S[0][ct], 0, 0, 0);
        S[1][ct] = __builtin_amdgcn_mfma_f32_16x16x32_bf16(qf[1][ks], kf, S[1][ct], 0, 0, 0);
      }
    }
    // no barrier: Ps is a separate buffer, each wave's rows are private

    // p = exp2(s*scale*log2e); write Ps (128x64, row-swizzled)
    const bool needmask = (kn >= 2 * bm);
    const int jbase = (kn - 2 * bm) * 64;
    const int hi = n >> 3, lo = n & 7;
#pragma unroll
    for (int mt = 0; mt < 2; ++mt) {
#pragma unroll
      for (int r = 0; r < 4; ++r) {
        int prow = 32 * w + 16 * mt + quad * 4 + r;
        float p0 = exp2f(S[mt][0][r] * kScaleLog2);
        float p1 = exp2f(S[mt][1][r] * kScaleLog2);
        float p2 = exp2f(S[mt][2][r] * kScaleLog2);
        float p3 = exp2f(S[mt][3][r] * kScaleLog2);
        if (needmask) {
          if (jbase + n > prow) p0 = 0.f;
          if (jbase + 16 + n > prow) p1 = 0.f;
          if (jbase + 32 + n > prow) p2 = 0.f;
          if (jbase + 48 + n > prow) p3 = 0.f;
        }
        int sw = prow & 7;
        Ps[prow * 64 + (((0 + hi) ^ sw) << 3) + lo] = f2bf(p0);
        Ps[prow * 64 + (((2 + hi) ^ sw) << 3) + lo] = f2bf(p1);
        Ps[prow * 64 + (((4 + hi) ^ sw) << 3) + lo] = f2bf(p2);
        Ps[prow * 64 + (((6 + hi) ^ sw) << 3) + lo] = f2bf(p3);
      }
    }
    __asm__ volatile("s_waitcnt lgkmcnt(0)" ::: "memory");  // own-wave Ps visible

    // O += P V ; Ol += P @ ones  (vf shared across both m-tiles)
#pragma unroll
    for (int ks = 0; ks < 2; ++ks) {
      int r0 = 32 * w + n, r1 = 32 * w + 16 + n;
      short8 pf0 = *(const short8*)(Ps + r0 * 64 + (((4 * ks + quad) ^ (r0 & 7)) << 3));
      short8 pf1 = *(const short8*)(Ps + r1 * 64 + (((4 * ks + quad) ^ (r1 & 7)) << 3));
      Ol[0] = __builtin_amdgcn_mfma_f32_16x16x32_bf16(pf0, lfrag, Ol[0], 0, 0, 0);
      Ol[1] = __builtin_amdgcn_mfma_f32_16x16x32_bf16(pf1, lfrag, Ol[1], 0, 0, 0);
#pragma unroll
      for (int dt = 0; dt < 8; ++dt) {
        int d = 16 * dt + n;
        short8 vf = *(const short8*)(Vt + d * 64 + (((4 * ks + quad) ^ (d & 7)) << 3));
        O[0][dt] = __builtin_amdgcn_mfma_f32_16x16x32_bf16(pf0, vf, O[0][dt], 0, 0, 0);
        O[1][dt] = __builtin_amdgcn_mfma_f32_16x16x32_bf16(pf1, vf, O[1][dt], 0, 0, 0);
      }
    }
  }

  // epilogue: l broadcast, normalize, gate, store bf16
#pragma unroll
  for (int mt = 0; mt < 2; ++mt) {
#pragma unroll
    for (int r = 0; r < 4; ++r) {
      float l = __shfl(Ol[mt][r], quad << 4, 64);
      float inv = 1.0f / l;
      int row = q0 + 32 * w + 16 * mt + quad * 4 + r;
#pragma unroll
      for (int dt = 0; dt < 8; ++dt) {
        int col = 16 * dt + n;
        float gte = qkvf[(long)row * kNqkv + 256 * h + 128 + col];
        og[(long)row * kHid + 128 * h + col] = f2bf(O[mt][dt][r] * inv * gte);
      }
    }
  }
}

extern "C" void kernel_launch(void* const* d_in, const int* in_sizes, int n_in,
                              void* d_out, int out_size, void* d_ws, size_t ws_size,
                              hipStream_t stream) {
  (void)in_sizes; (void)n_in; (void)out_size; (void)ws_size;
  const float* hs   = (const float*)d_in[0];
  const float* cosb = (const float*)d_in[1];
  const float* sinb = (const float*)d_in[2];
  const float* wqkv = (const float*)d_in[3];
  const float* wo   = (const float*)d_in[4];
  const float* qw   = (const float*)d_in[5];
  const float* kw   = (const float*)d_in[6];
  float* out = (float*)d_out;

  char* ws = (char*)d_ws;
  float* qkv = (float*)ws;                                    // 75.5 MB fp32
  unsigned short* hsb = (unsigned short*)(ws + 75497472);     // 16.8 MB (aliases og)
  unsigned short* og  = hsb;                                  // written after hsb dead
  unsigned short* wt  = (unsigned short*)(ws + 92274688);     // 18.9 MB shared
  unsigned short* VtG = wt;  // aliases dead w_qkv^T during flash (w_o^T written after)

  cvt_bf16<<<dim3(8192), 256, 0, stream>>>(hs, hsb, (long)kT * kHid);
  transpose_cvt<<<dim3(kNqkv / 32, kHid / 32), 256, 0, stream>>>(wqkv, wt, kHid, kNqkv);
  gemm_bf16<<<dim3(kT / 128, kNqkv / 128), 256, 0, stream>>>(hsb, wt, qkv, kT, kNqkv, kHid);
  vt_transpose<<<dim3(kT / 32, 8), 256, 0, stream>>>(qkv, VtG);
  norm_rope_cvt<<<dim3(2304), 256, 0, stream>>>(qkv, cosb, sinb, qw, kw);
  flash_attn_mfma<<<dim3(kT / 128 * kH), 256, 0, stream>>>((const unsigned short*)qkv, qkv, VtG, og);
  transpose_cvt<<<dim3(kHid / 32, kHid / 32), 256, 0, stream>>>(wo, wt, kHid, kHid);
  gemm_bf16<<<dim3(kT / 128, kHid / 128), 256, 0, stream>>>(og, wt, out, kT, kHid, kHid);
}

// Round 15
// 482.611 us; speedup vs baseline: 1.1802x; 1.0299x over previous
//
#include <hip/hip_runtime.h>
#include <hip/hip_bf16.h>
#include <math.h>

// Qwen3.5 attention block, bf16-MFMA everywhere.
// cvt(hs), transpose_cvt(w_qkv) -> gemm_bf16(QKV, 128^2, XCD swizzle) ->
// vt_transpose -> norm_rope_cvt (wave-parallel) ->
// flash_attn_mfma v10 (__expf; exp2f regressed +18us, VALUBusy 29->34) ->
// transpose_cvt(w_o) -> gemm_bf16(out).
//
// Structural notes (session evidence, 14 rounds):
// - 128^2 GEMM tile is grid-optimal for these shapes (QKV grid 32x36=1152
//   blocks, 2.5/CU backfill). 256^2 tiles -> 288-block grid at 1 blk/CU
//   (128KB LDS) -> makespan 2x per-tile time (56% util): refuted (r12/r13).
// - flash: per-tile cost saturates at ~2.5us/tile/CU regardless of TLP
//   (2 vs 3 vs 6 blocks/CU all equal); barrier-removal via dedicated Ps
//   was the only structural win. Split-K linear-combine: flash -4us but
//   +10us combine = net loss. L2-direct (no staging): latency-bound, 2.6x.
// - __expf lowers to v_mul+v_exp (fast); exp2f is precise-path, MORE valu.

namespace {
constexpr int kT   = 4096;
constexpr int kHid = 2048;
constexpr int kH   = 16;
constexpr int kHkv = 2;
constexpr int kD   = 128;
constexpr int kNqkv = (2 * kH + 2 * kHkv) * kD;  // 4608 floats per row
constexpr int kQsz  = 2 * kH * kD;               // 4096
constexpr int kRowU = kNqkv * 2;                 // 9216 ushorts per row
constexpr float kEps = 1e-6f;
constexpr float kScale = 0.08838834764831845f;   // 128^-0.5
}

typedef __attribute__((ext_vector_type(8))) short short8;
typedef __attribute__((ext_vector_type(4))) float floatx4;

__device__ inline unsigned short f2bf(float x) {
  unsigned u = __float_as_uint(x);
  u = (u + 0x7fffu + ((u >> 16) & 1u)) >> 16;
  return (unsigned short)u;
}

__device__ inline void gload_lds16(const void* g, void* l) {
  typedef const __attribute__((address_space(1))) unsigned GQ;
  typedef __attribute__((address_space(3))) unsigned LQ;
  __builtin_amdgcn_global_load_lds((GQ*)g, (LQ*)l, 16, 0, 0);
}

// ---- fp32 -> bf16 elementwise ----
__global__ __launch_bounds__(256)
void cvt_bf16(const float* __restrict__ in, unsigned short* __restrict__ out,
              long nelem) {
  long i = ((long)blockIdx.x * 256 + threadIdx.x) * 4;
  if (i >= nelem) return;
  float4 v = *(const float4*)(in + i);
  unsigned long long p = (unsigned long long)f2bf(v.x) |
                         ((unsigned long long)f2bf(v.y) << 16) |
                         ((unsigned long long)f2bf(v.z) << 32) |
                         ((unsigned long long)f2bf(v.w) << 48);
  *(unsigned long long*)(out + i) = p;
}

// ---- fp32 [R][C] -> bf16 [C][R] tiled transpose ----
__global__ __launch_bounds__(256)
void transpose_cvt(const float* __restrict__ in, unsigned short* __restrict__ out,
                   int R, int C) {
  __shared__ float t[32][33];
  const int bx = blockIdx.x * 32;
  const int by = blockIdx.y * 32;
  const int x = threadIdx.x & 31, y = threadIdx.x >> 5;
#pragma unroll
  for (int j = 0; j < 4; ++j)
    t[y * 4 + j][x] = in[(long)(by + y * 4 + j) * C + bx + x];
  __syncthreads();
#pragma unroll
  for (int j = 0; j < 4; ++j)
    out[(long)(bx + y * 4 + j) * R + by + x] = f2bf(t[x][y * 4 + j]);
}

// ---- V^T pre-transpose: qkv fp32 V (rows t, 256 cols) -> VtG bf16 [256][T] ----
__global__ __launch_bounds__(256)
void vt_transpose(const float* __restrict__ qkv, unsigned short* __restrict__ VtG) {
  __shared__ float t[32][33];
  const int t0 = blockIdx.x * 32;
  const int c0 = blockIdx.y * 32;
  const int x = threadIdx.x & 31, y = threadIdx.x >> 5;
#pragma unroll
  for (int j = 0; j < 4; ++j)
    t[y * 4 + j][x] = qkv[(long)(t0 + y * 4 + j) * kNqkv + 4352 + c0 + x];
  __syncthreads();
#pragma unroll
  for (int j = 0; j < 4; ++j)
    VtG[(long)(c0 + y * 4 + j) * kT + t0 + x] = f2bf(t[x][y * 4 + j]);
}

// ---- C[M,N] fp32 = A[M,K]bf16 @ Bt[N,K]bf16^T. 128x128 tile, BK=64. ----
// XCD-band swizzle (kept from best build).
__global__ __launch_bounds__(256)
void gemm_bf16(const unsigned short* __restrict__ A,
               const unsigned short* __restrict__ Bt, float* __restrict__ C,
               int M, int N, int K) {
  __shared__ __align__(16) unsigned short As[128 * 64];
  __shared__ __align__(16) unsigned short Bs[128 * 64];
  const int tid = threadIdx.x;
  const int lane = tid & 63;
  const int w = tid >> 6;
  const int wr = w >> 1, wc = w & 1;
  const int n = lane & 15;
  const int quad = lane >> 4;

  int bx = blockIdx.x, by = blockIdx.y;
  const int nbx = gridDim.x, nby = gridDim.y;
  if (nbx == 32 && ((nbx * nby) & 7) == 0) {
    int lin = bx + nbx * by;        // dispatch-linear id (x fastest)
    int xcd = lin & 7, s = lin >> 3;
    bx = 4 * xcd + (s & 3);
    by = s >> 2;
  }
  const long bm = (long)bx * 128, bn = (long)by * 128;

  floatx4 acc[4][4];
  floatx4 zero = {0.f, 0.f, 0.f, 0.f};
#pragma unroll
  for (int a = 0; a < 4; ++a)
#pragma unroll
    for (int b = 0; b < 4; ++b) acc[a][b] = zero;

  for (int k0 = 0; k0 < K; k0 += 64) {
    __syncthreads();
#pragma unroll
    for (int it = 0; it < 4; ++it) {
      int ci = it * 256 + tid;            // 16B chunk id 0..1023
      int r = ci >> 3, c = ci & 7;
      int cg = c ^ (r & 7);               // global chunk for this slot
      gload_lds16(A + (bm + r) * (long)K + k0 + cg * 8, As + (it * 256 + w * 64) * 8);
      gload_lds16(Bt + (bn + r) * (long)K + k0 + cg * 8, Bs + (it * 256 + w * 64) * 8);
    }
    __syncthreads();

#pragma unroll
    for (int ks = 0; ks < 2; ++ks) {
      short8 af[4], bf[4];
#pragma unroll
      for (int a = 0; a < 4; ++a) {
        int m = wr * 64 + a * 16 + n;
        af[a] = *(const short8*)(As + m * 64 + ((4 * ks + quad) ^ (m & 7)) * 8);
      }
#pragma unroll
      for (int b = 0; b < 4; ++b) {
        int nn = wc * 64 + b * 16 + n;
        bf[b] = *(const short8*)(Bs + nn * 64 + ((4 * ks + quad) ^ (nn & 7)) * 8);
      }
#pragma unroll
      for (int a = 0; a < 4; ++a)
#pragma unroll
        for (int b = 0; b < 4; ++b)
          acc[a][b] = __builtin_amdgcn_mfma_f32_16x16x32_bf16(af[a], bf[b], acc[a][b], 0, 0, 0);
    }
  }
#pragma unroll
  for (int a = 0; a < 4; ++a)
#pragma unroll
    for (int b = 0; b < 4; ++b)
#pragma unroll
      for (int r = 0; r < 4; ++r)
        C[(bm + wr * 64 + a * 16 + quad * 4 + r) * (long)N + bn + wc * 64 + b * 16 + n] =
            acc[a][b][r];
}

// ------- RMSNorm + RoPE + bf16 pack (q,k), wave-parallel, barrier-free -------
__global__ __launch_bounds__(256)
void norm_rope_cvt(float* qkv, const float* __restrict__ cosb,
                   const float* __restrict__ sinb, const float* __restrict__ qw,
                   const float* __restrict__ kw) {
  unsigned short* qkvu = (unsigned short*)qkv;
  const int lane = threadIdx.x & 63;
  const int wslot = blockIdx.x * 4 + (threadIdx.x >> 6);
  const int nslots = gridDim.x * 4;
  for (int task = wslot; task < kT * 18; task += nslots) {
    const int t = task / 18;
    const int h = task % 18;
    const bool isq = (h < kH);
    const long base = (long)t * kNqkv + (isq ? h * 2 * kD : kQsz + (h - kH) * kD);
    float xlo = qkv[base + lane];
    float xhi = qkv[base + 64 + lane];
    float v = xlo * xlo + xhi * xhi;
#pragma unroll
    for (int off = 1; off < 64; off <<= 1) v += __shfl_xor(v, off, 64);
    float rms = rsqrtf(v * (1.0f / kD) + kEps);
    const float* wv = isq ? qw : kw;
    float nlo = xlo * rms * wv[lane];
    float nhi = xhi * rms * wv[64 + lane];
    float clo = cosb[t * kD + lane], chi = cosb[t * kD + 64 + lane];
    float slo = sinb[t * kD + lane], shi = sinb[t * kD + 64 + lane];
    float rlo = nlo * clo - nhi * slo;   // rot(lo) = -x[l+64]
    float rhi = nhi * chi + nlo * shi;   // rot(hi) = +x[l]
    if (isq) {
      float glo = qkv[base + kD + lane];
      float ghi = qkv[base + kD + 64 + lane];
      qkv[base + kD + lane] = 1.0f / (1.0f + __expf(-glo));
      qkv[base + kD + 64 + lane] = 1.0f / (1.0f + __expf(-ghi));
      qkvu[(long)t * kRowU + 512 * h + lane] = f2bf(rlo);
      qkvu[(long)t * kRowU + 512 * h + 64 + lane] = f2bf(rhi);
    } else {
      qkvu[(long)t * kRowU + 8192 + 256 * (h - kH) + lane] = f2bf(rlo);
      qkvu[(long)t * kRowU + 8192 + 256 * (h - kH) + 64 + lane] = f2bf(rhi);
    }
  }
}

// ---------------- bf16 MFMA flash attention v10 (best: 165-167us) -----------
// v3 structure + dedicated Ps buffer (barrier (3) removed; 2 barriers/tile).
__global__ __launch_bounds__(256)
void flash_attn_mfma(const unsigned short* qkvu, const float* qkvf,
                     const unsigned short* VtG, unsigned short* __restrict__ og) {
  __shared__ __align__(16) unsigned short Ks[64 * 128];  // K tile (swizzled)
  __shared__ __align__(16) unsigned short Vt[128 * 64];  // V^T tile (swizzled)
  __shared__ __align__(16) unsigned short Ps[128 * 64];  // P tile (row-swizzled)

  const int tid = threadIdx.x;
  const int lane = tid & 63;
  const int w = tid >> 6;
  const int n = lane & 15;
  const int quad = lane >> 4;
  const int g = blockIdx.x;
  const int h = g & 15;
  const int bm = 31 - (g >> 4);   // heavy-first
  const int hk = h >> 3;
  const int q0 = bm * 128;

  short8 qf[2][4];
#pragma unroll
  for (int mt = 0; mt < 2; ++mt) {
    const unsigned short* qrow =
        qkvu + (long)(q0 + 32 * w + 16 * mt + n) * kRowU + 512 * h;
#pragma unroll
    for (int ks = 0; ks < 4; ++ks)
      qf[mt][ks] = *(const short8*)(qrow + 32 * ks + 8 * quad);
  }
  short8 lfrag;  // B-frag: col 0 = ones -> row-sum accumulator
  {
    short o = (n == 0) ? (short)0x3F80 : (short)0;
    lfrag = (short8){o, o, o, o, o, o, o, o};
  }

  floatx4 O[2][8];
  floatx4 Ol[2];
  floatx4 zero = {0.f, 0.f, 0.f, 0.f};
#pragma unroll
  for (int mt = 0; mt < 2; ++mt) {
    Ol[mt] = zero;
#pragma unroll
    for (int dt = 0; dt < 8; ++dt) O[mt][dt] = zero;
  }

  const int kn_end = 2 * bm + 1;
  for (int kn = 0; kn <= kn_end; ++kn) {
    __syncthreads();  // (1) prev QK+PV reads done before restage
    // stage K: 64 rows x 128 d, chunk swizzle c ^ (r&15)
#pragma unroll
    for (int it = 0; it < 4; ++it) {
      int pc = (w * 4 + it) * 64 + lane;
      int r = pc >> 4, c = pc & 15;
      int lc = c ^ (r & 15);
      gload_lds16(qkvu + (long)(kn * 64 + r) * kRowU + 8192 + 256 * hk + 8 * lc,
                  Ks + (w * 4 + it) * 512);
    }
    // stage V^T: 128 rows (d) x 64 keys, chunk swizzle c ^ (d&7)
#pragma unroll
    for (int it = 0; it < 4; ++it) {
      int pc = (w * 4 + it) * 64 + lane;
      int d = pc >> 3, c = pc & 7;
      int lc = c ^ (d & 7);
      gload_lds16(VtG + (long)hk * (128 * kT) + (long)d * kT + kn * 64 + 8 * lc,
                  Vt + (w * 4 + it) * 512);
    }
    __syncthreads();  // (2) staging complete

    // S = Q K^T  (kf shared across both m-tiles)
    floatx4 S[2][4];
#pragma unroll
    for (int mt = 0; mt < 2; ++mt)
#pragma unroll
      for (int ct = 0; ct < 4; ++ct) S[mt][ct] = zero;
#pragma unroll
    for (int ks = 0; ks < 4; ++ks) {
#pragma unroll
      for (int ct = 0; ct < 4; ++ct) {
        int row = 16 * ct + n;
        short8 kf = *(const short8*)(Ks + row * 128 + ((4 * ks + quad) ^ n) * 8);
        S[0][ct] = __builtin_amdgcn_mfma_f32_16x16x32_bf16(qf[0][ks], kf, S[0][ct], 0, 0, 0);
        S[1][ct] = __builtin_amdgcn_mfma_f32_16x16x32_bf16(qf[1][ks], kf, S[1][ct], 0, 0, 0);
      }
    }
    // no barrier: Ps is a separate buffer, each wave's rows are private

    // p = exp(s*scale); write Ps (128 rows x 64 cols, row-swizzled)
    const bool needmask = (kn >= 2 * bm);
    const int jbase = (kn - 2 * bm) * 64;
    const int hi = n >> 3, lo = n & 7;
#pragma unroll
    for (int mt = 0; mt < 2; ++mt) {
#pragma unroll
      for (int r = 0; r < 4; ++r) {
        int prow = 32 * w + 16 * mt + quad * 4 + r;
        float p0 = __expf(S[mt][0][r] * kScale);
        float p1 = __expf(S[mt][1][r] * kScale);
        float p2 = __expf(S[mt][2][r] * kScale);
        float p3 = __expf(S[mt][3][r] * kScale);
        if (needmask) {
          if (jbase + n > prow) p0 = 0.f;
          if (jbase + 16 + n > prow) p1 = 0.f;
          if (jbase + 32 + n > prow) p2 = 0.f;
          if (jbase + 48 + n > prow) p3 = 0.f;
        }
        int sw = prow & 7;
        Ps[prow * 64 + (((0 + hi) ^ sw) << 3) + lo] = f2bf(p0);
        Ps[prow * 64 + (((2 + hi) ^ sw) << 3) + lo] = f2bf(p1);
        Ps[prow * 64 + (((4 + hi) ^ sw) << 3) + lo] = f2bf(p2);
        Ps[prow * 64 + (((6 + hi) ^ sw) << 3) + lo] = f2bf(p3);
      }
    }
    __asm__ volatile("s_waitcnt lgkmcnt(0)" ::: "memory");  // own-wave Ps visible

    // O += P V ; Ol += P @ ones  (vf shared across both m-tiles)
#pragma unroll
    for (int ks = 0; ks < 2; ++ks) {
      int r0 = 32 * w + n, r1 = 32 * w + 16 + n;
      short8 pf0 = *(const short8*)(Ps + r0 * 64 + (((4 * ks + quad) ^ (r0 & 7)) << 3));
      short8 pf1 = *(const short8*)(Ps + r1 * 64 + (((4 * ks + quad) ^ (r1 & 7)) << 3));
      Ol[0] = __builtin_amdgcn_mfma_f32_16x16x32_bf16(pf0, lfrag, Ol[0], 0, 0, 0);
      Ol[1] = __builtin_amdgcn_mfma_f32_16x16x32_bf16(pf1, lfrag, Ol[1], 0, 0, 0);
#pragma unroll
      for (int dt = 0; dt < 8; ++dt) {
        int d = 16 * dt + n;
        short8 vf = *(const short8*)(Vt + d * 64 + (((4 * ks + quad) ^ (d & 7)) << 3));
        O[0][dt] = __builtin_amdgcn_mfma_f32_16x16x32_bf16(pf0, vf, O[0][dt], 0, 0, 0);
        O[1][dt] = __builtin_amdgcn_mfma_f32_16x16x32_bf16(pf1, vf, O[1][dt], 0, 0, 0);
      }
    }
  }

  // epilogue: l broadcast, normalize, gate, store bf16
#pragma unroll
  for (int mt = 0; mt < 2; ++mt) {
#pragma unroll
    for (int r = 0; r < 4; ++r) {
      float l = __shfl(Ol[mt][r], quad << 4, 64);
      float inv = 1.0f / l;
      int row = q0 + 32 * w + 16 * mt + quad * 4 + r;
#pragma unroll
      for (int dt = 0; dt < 8; ++dt) {
        int col = 16 * dt + n;
        float gte = qkvf[(long)row * kNqkv + 256 * h + 128 + col];
        og[(long)row * kHid + 128 * h + col] = f2bf(O[mt][dt][r] * inv * gte);
      }
    }
  }
}

extern "C" void kernel_launch(void* const* d_in, const int* in_sizes, int n_in,
                              void* d_out, int out_size, void* d_ws, size_t ws_size,
                              hipStream_t stream) {
  (void)in_sizes; (void)n_in; (void)out_size; (void)ws_size;
  const float* hs   = (const float*)d_in[0];
  const float* cosb = (const float*)d_in[1];
  const float* sinb = (const float*)d_in[2];
  const float* wqkv = (const float*)d_in[3];
  const float* wo   = (const float*)d_in[4];
  const float* qw   = (const float*)d_in[5];
  const float* kw   = (const float*)d_in[6];
  float* out = (float*)d_out;

  char* ws = (char*)d_ws;
  float* qkv = (float*)ws;                                    // 75.5 MB fp32
  unsigned short* hsb = (unsigned short*)(ws + 75497472);     // 16.8 MB (aliases og)
  unsigned short* og  = hsb;                                  // written after hsb dead
  unsigned short* wt  = (unsigned short*)(ws + 92274688);     // 18.9 MB shared
  unsigned short* VtG = wt;  // aliases dead w_qkv^T during flash (w_o^T written after)

  cvt_bf16<<<dim3(8192), 256, 0, stream>>>(hs, hsb, (long)kT * kHid);
  transpose_cvt<<<dim3(kNqkv / 32, kHid / 32), 256, 0, stream>>>(wqkv, wt, kHid, kNqkv);
  gemm_bf16<<<dim3(kT / 128, kNqkv / 128), 256, 0, stream>>>(hsb, wt, qkv, kT, kNqkv, kHid);
  vt_transpose<<<dim3(kT / 32, 8), 256, 0, stream>>>(qkv, VtG);
  norm_rope_cvt<<<dim3(2304), 256, 0, stream>>>(qkv, cosb, sinb, qw, kw);
  flash_attn_mfma<<<dim3(kT / 128 * kH), 256, 0, stream>>>((const unsigned short*)qkv, qkv, VtG, og);
  transpose_cvt<<<dim3(kHid / 32, kHid / 32), 256, 0, stream>>>(wo, wt, kHid, kHid);
  gemm_bf16<<<dim3(kT / 128, kHid / 128), 256, 0, stream>>>(og, wt, out, kT, kHid, kHid);
}

// Round 16
// 476.653 us; speedup vs baseline: 1.1949x; 1.0125x over previous
//
#include <hip/hip_runtime.h>
#include <hip/hip_bf16.h>
#include <math.h>

// Qwen3.5 attention block, bf16-MFMA everywhere. 6 dispatches:
// prep_inputs (cvt(hs) + transpose_cvt(w_qkv) fused) -> gemm_bf16(QKV) ->
// vt_rope (vt_transpose + norm_rope fused) -> flash_attn_mfma v10 ->
// transpose_cvt(w_o) -> gemm_bf16(out).
//
// Structural notes (session evidence, 15 rounds):
// - 128^2 GEMM tile is grid-optimal for these shapes; 256^2 grids quantize
//   badly (288 blocks / 256 CUs at 1 blk/CU = 56% util): refuted r12/r13.
// - flash: per-tile cost saturates ~2.5us/tile/CU regardless of TLP;
//   barrier-removal via dedicated Ps was the structural win. Split-K,
//   dbuf, pairing, BN/BM scaling, L2-direct: all refuted with counters.
// - __expf lowers to v_mul+v_exp (fast path); exp2f is precise-path (r14).

namespace {
constexpr int kT   = 4096;
constexpr int kHid = 2048;
constexpr int kH   = 16;
constexpr int kHkv = 2;
constexpr int kD   = 128;
constexpr int kNqkv = (2 * kH + 2 * kHkv) * kD;  // 4608 floats per row
constexpr int kQsz  = 2 * kH * kD;               // 4096
constexpr int kRowU = kNqkv * 2;                 // 9216 ushorts per row
constexpr float kEps = 1e-6f;
constexpr float kScale = 0.08838834764831845f;   // 128^-0.5
}

typedef __attribute__((ext_vector_type(8))) short short8;
typedef __attribute__((ext_vector_type(4))) float floatx4;

__device__ inline unsigned short f2bf(float x) {
  unsigned u = __float_as_uint(x);
  u = (u + 0x7fffu + ((u >> 16) & 1u)) >> 16;
  return (unsigned short)u;
}

__device__ inline void gload_lds16(const void* g, void* l) {
  typedef const __attribute__((address_space(1))) unsigned GQ;
  typedef __attribute__((address_space(3))) unsigned LQ;
  __builtin_amdgcn_global_load_lds((GQ*)g, (LQ*)l, 16, 0, 0);
}

// ---- fused: cvt_bf16(hs) [blocks 0..8191] +
//             transpose_cvt(w_qkv 2048x4608 -> wt 4608x2048) [8192..17407] ----
__global__ __launch_bounds__(256)
void prep_inputs(const float* __restrict__ hs, unsigned short* __restrict__ hsb,
                 const float* __restrict__ wqkv, unsigned short* __restrict__ wt) {
  __shared__ float t[32][33];
  const int b = blockIdx.x;
  if (b < 8192) {
    long i = ((long)b * 256 + threadIdx.x) * 4;
    float4 v = *(const float4*)(hs + i);
    unsigned long long p = (unsigned long long)f2bf(v.x) |
                           ((unsigned long long)f2bf(v.y) << 16) |
                           ((unsigned long long)f2bf(v.z) << 32) |
                           ((unsigned long long)f2bf(v.w) << 48);
    *(unsigned long long*)(hsb + i) = p;
    return;
  }
  const int b2 = b - 8192;                  // 0..9215
  const int bx = (b2 % 144) * 32;           // col tile in w_qkv
  const int by = (b2 / 144) * 32;           // row tile
  const int x = threadIdx.x & 31, y = threadIdx.x >> 5;
#pragma unroll
  for (int j = 0; j < 4; ++j)
    t[y * 4 + j][x] = wqkv[(long)(by + y * 4 + j) * kNqkv + bx + x];
  __syncthreads();
#pragma unroll
  for (int j = 0; j < 4; ++j)
    wt[(long)(bx + y * 4 + j) * kHid + by + x] = f2bf(t[x][y * 4 + j]);
}

// ---- fp32 [R][C] -> bf16 [C][R] tiled transpose (w_o) ----
__global__ __launch_bounds__(256)
void transpose_cvt(const float* __restrict__ in, unsigned short* __restrict__ out,
                   int R, int C) {
  __shared__ float t[32][33];
  const int bx = blockIdx.x * 32;
  const int by = blockIdx.y * 32;
  const int x = threadIdx.x & 31, y = threadIdx.x >> 5;
#pragma unroll
  for (int j = 0; j < 4; ++j)
    t[y * 4 + j][x] = in[(long)(by + y * 4 + j) * C + bx + x];
  __syncthreads();
#pragma unroll
  for (int j = 0; j < 4; ++j)
    out[(long)(bx + y * 4 + j) * R + by + x] = f2bf(t[x][y * 4 + j]);
}

// ---- C[M,N] fp32 = A[M,K]bf16 @ Bt[N,K]bf16^T. 128x128 tile, BK=64. ----
// XCD-band swizzle (kept from best build).
__global__ __launch_bounds__(256)
void gemm_bf16(const unsigned short* __restrict__ A,
               const unsigned short* __restrict__ Bt, float* __restrict__ C,
               int M, int N, int K) {
  __shared__ __align__(16) unsigned short As[128 * 64];
  __shared__ __align__(16) unsigned short Bs[128 * 64];
  const int tid = threadIdx.x;
  const int lane = tid & 63;
  const int w = tid >> 6;
  const int wr = w >> 1, wc = w & 1;
  const int n = lane & 15;
  const int quad = lane >> 4;

  int bx = blockIdx.x, by = blockIdx.y;
  const int nbx = gridDim.x, nby = gridDim.y;
  if (nbx == 32 && ((nbx * nby) & 7) == 0) {
    int lin = bx + nbx * by;        // dispatch-linear id (x fastest)
    int xcd = lin & 7, s = lin >> 3;
    bx = 4 * xcd + (s & 3);
    by = s >> 2;
  }
  const long bm = (long)bx * 128, bn = (long)by * 128;

  floatx4 acc[4][4];
  floatx4 zero = {0.f, 0.f, 0.f, 0.f};
#pragma unroll
  for (int a = 0; a < 4; ++a)
#pragma unroll
    for (int b = 0; b < 4; ++b) acc[a][b] = zero;

  for (int k0 = 0; k0 < K; k0 += 64) {
    __syncthreads();
#pragma unroll
    for (int it = 0; it < 4; ++it) {
      int ci = it * 256 + tid;            // 16B chunk id 0..1023
      int r = ci >> 3, c = ci & 7;
      int cg = c ^ (r & 7);               // global chunk for this slot
      gload_lds16(A + (bm + r) * (long)K + k0 + cg * 8, As + (it * 256 + w * 64) * 8);
      gload_lds16(Bt + (bn + r) * (long)K + k0 + cg * 8, Bs + (it * 256 + w * 64) * 8);
    }
    __syncthreads();

#pragma unroll
    for (int ks = 0; ks < 2; ++ks) {
      short8 af[4], bf[4];
#pragma unroll
      for (int a = 0; a < 4; ++a) {
        int m = wr * 64 + a * 16 + n;
        af[a] = *(const short8*)(As + m * 64 + ((4 * ks + quad) ^ (m & 7)) * 8);
      }
#pragma unroll
      for (int b = 0; b < 4; ++b) {
        int nn = wc * 64 + b * 16 + n;
        bf[b] = *(const short8*)(Bs + nn * 64 + ((4 * ks + quad) ^ (nn & 7)) * 8);
      }
#pragma unroll
      for (int a = 0; a < 4; ++a)
#pragma unroll
        for (int b = 0; b < 4; ++b)
          acc[a][b] = __builtin_amdgcn_mfma_f32_16x16x32_bf16(af[a], bf[b], acc[a][b], 0, 0, 0);
    }
  }
#pragma unroll
  for (int a = 0; a < 4; ++a)
#pragma unroll
    for (int b = 0; b < 4; ++b)
#pragma unroll
      for (int r = 0; r < 4; ++r)
        C[(bm + wr * 64 + a * 16 + quad * 4 + r) * (long)N + bn + wc * 64 + b * 16 + n] =
            acc[a][b][r];
}

// ---- fused: vt_transpose [blocks 0..1023] + norm_rope [1024..3327] ----
// vt reads V fp32 cols 4352..4607; rope writes packed q/k bf16 (ushort
// 0..8703) + gate fp32 cols h*256+128..255. Disjoint regions -> safe.
__global__ __launch_bounds__(256)
void vt_rope(float* qkv, unsigned short* __restrict__ VtG,
             const float* __restrict__ cosb, const float* __restrict__ sinb,
             const float* __restrict__ qw, const float* __restrict__ kw) {
  __shared__ float t[32][33];
  const int b = blockIdx.x;
  if (b < 1024) {
    const int t0 = (b & 127) * 32;
    const int c0 = (b >> 7) * 32;
    const int x = threadIdx.x & 31, y = threadIdx.x >> 5;
#pragma unroll
    for (int j = 0; j < 4; ++j)
      t[y * 4 + j][x] = qkv[(long)(t0 + y * 4 + j) * kNqkv + 4352 + c0 + x];
    __syncthreads();
#pragma unroll
    for (int j = 0; j < 4; ++j)
      VtG[(long)(c0 + y * 4 + j) * kT + t0 + x] = f2bf(t[x][y * 4 + j]);
    return;
  }
  unsigned short* qkvu = (unsigned short*)qkv;
  const int lane = threadIdx.x & 63;
  const int wslot = (b - 1024) * 4 + (threadIdx.x >> 6);
  const int nslots = 2304 * 4;
  for (int task = wslot; task < kT * 18; task += nslots) {
    const int tt = task / 18;
    const int h = task % 18;
    const bool isq = (h < kH);
    const long base = (long)tt * kNqkv + (isq ? h * 2 * kD : kQsz + (h - kH) * kD);
    float xlo = qkv[base + lane];
    float xhi = qkv[base + 64 + lane];
    float v = xlo * xlo + xhi * xhi;
#pragma unroll
    for (int off = 1; off < 64; off <<= 1) v += __shfl_xor(v, off, 64);
    float rms = rsqrtf(v * (1.0f / kD) + kEps);
    const float* wv = isq ? qw : kw;
    float nlo = xlo * rms * wv[lane];
    float nhi = xhi * rms * wv[64 + lane];
    float clo = cosb[tt * kD + lane], chi = cosb[tt * kD + 64 + lane];
    float slo = sinb[tt * kD + lane], shi = sinb[tt * kD + 64 + lane];
    float rlo = nlo * clo - nhi * slo;   // rot(lo) = -x[l+64]
    float rhi = nhi * chi + nlo * shi;   // rot(hi) = +x[l]
    if (isq) {
      float glo = qkv[base + kD + lane];
      float ghi = qkv[base + kD + 64 + lane];
      qkv[base + kD + lane] = 1.0f / (1.0f + __expf(-glo));
      qkv[base + kD + 64 + lane] = 1.0f / (1.0f + __expf(-ghi));
      qkvu[(long)tt * kRowU + 512 * h + lane] = f2bf(rlo);
      qkvu[(long)tt * kRowU + 512 * h + 64 + lane] = f2bf(rhi);
    } else {
      qkvu[(long)tt * kRowU + 8192 + 256 * (h - kH) + lane] = f2bf(rlo);
      qkvu[(long)tt * kRowU + 8192 + 256 * (h - kH) + 64 + lane] = f2bf(rhi);
    }
  }
}

// ---------------- bf16 MFMA flash attention v10 (best: 165-167us) -----------
// v3 structure + dedicated Ps buffer (barrier (3) removed; 2 barriers/tile).
__global__ __launch_bounds__(256)
void flash_attn_mfma(const unsigned short* qkvu, const float* qkvf,
                     const unsigned short* VtG, unsigned short* __restrict__ og) {
  __shared__ __align__(16) unsigned short Ks[64 * 128];  // K tile (swizzled)
  __shared__ __align__(16) unsigned short Vt[128 * 64];  // V^T tile (swizzled)
  __shared__ __align__(16) unsigned short Ps[128 * 64];  // P tile (row-swizzled)

  const int tid = threadIdx.x;
  const int lane = tid & 63;
  const int w = tid >> 6;
  const int n = lane & 15;
  const int quad = lane >> 4;
  const int g = blockIdx.x;
  const int h = g & 15;
  const int bm = 31 - (g >> 4);   // heavy-first
  const int hk = h >> 3;
  const int q0 = bm * 128;

  short8 qf[2][4];
#pragma unroll
  for (int mt = 0; mt < 2; ++mt) {
    const unsigned short* qrow =
        qkvu + (long)(q0 + 32 * w + 16 * mt + n) * kRowU + 512 * h;
#pragma unroll
    for (int ks = 0; ks < 4; ++ks)
      qf[mt][ks] = *(const short8*)(qrow + 32 * ks + 8 * quad);
  }
  short8 lfrag;  // B-frag: col 0 = ones -> row-sum accumulator
  {
    short o = (n == 0) ? (short)0x3F80 : (short)0;
    lfrag = (short8){o, o, o, o, o, o, o, o};
  }

  floatx4 O[2][8];
  floatx4 Ol[2];
  floatx4 zero = {0.f, 0.f, 0.f, 0.f};
#pragma unroll
  for (int mt = 0; mt < 2; ++mt) {
    Ol[mt] = zero;
#pragma unroll
    for (int dt = 0; dt < 8; ++dt) O[mt][dt] = zero;
  }

  const int kn_end = 2 * bm + 1;
  for (int kn = 0; kn <= kn_end; ++kn) {
    __syncthreads();  // (1) prev QK+PV reads done before restage
    // stage K: 64 rows x 128 d, chunk swizzle c ^ (r&15)
#pragma unroll
    for (int it = 0; it < 4; ++it) {
      int pc = (w * 4 + it) * 64 + lane;
      int r = pc >> 4, c = pc & 15;
      int lc = c ^ (r & 15);
      gload_lds16(qkvu + (long)(kn * 64 + r) * kRowU + 8192 + 256 * hk + 8 * lc,
                  Ks + (w * 4 + it) * 512);
    }
    // stage V^T: 128 rows (d) x 64 keys, chunk swizzle c ^ (d&7)
#pragma unroll
    for (int it = 0; it < 4; ++it) {
      int pc = (w * 4 + it) * 64 + lane;
      int d = pc >> 3, c = pc & 7;
      int lc = c ^ (d & 7);
      gload_lds16(VtG + (long)hk * (128 * kT) + (long)d * kT + kn * 64 + 8 * lc,
                  Vt + (w * 4 + it) * 512);
    }
    __syncthreads();  // (2) staging complete

    // S = Q K^T  (kf shared across both m-tiles)
    floatx4 S[2][4];
#pragma unroll
    for (int mt = 0; mt < 2; ++mt)
#pragma unroll
      for (int ct = 0; ct < 4; ++ct) S[mt][ct] = zero;
#pragma unroll
    for (int ks = 0; ks < 4; ++ks) {
#pragma unroll
      for (int ct = 0; ct < 4; ++ct) {
        int row = 16 * ct + n;
        short8 kf = *(const short8*)(Ks + row * 128 + ((4 * ks + quad) ^ n) * 8);
        S[0][ct] = __builtin_amdgcn_mfma_f32_16x16x32_bf16(qf[0][ks], kf, S[0][ct], 0, 0, 0);
        S[1][ct] = __builtin_amdgcn_mfma_f32_16x16x32_bf16(qf[1][ks], kf, S[1][ct], 0, 0, 0);
      }
    }
    // no barrier: Ps is a separate buffer, each wave's rows are private

    // p = exp(s*scale); write Ps (128 rows x 64 cols, row-swizzled)
    const bool needmask = (kn >= 2 * bm);
    const int jbase = (kn - 2 * bm) * 64;
    const int hi = n >> 3, lo = n & 7;
#pragma unroll
    for (int mt = 0; mt < 2; ++mt) {
#pragma unroll
      for (int r = 0; r < 4; ++r) {
        int prow = 32 * w + 16 * mt + quad * 4 + r;
        float p0 = __expf(S[mt][0][r] * kScale);
        float p1 = __expf(S[mt][1][r] * kScale);
        float p2 = __expf(S[mt][2][r] * kScale);
        float p3 = __expf(S[mt][3][r] * kScale);
        if (needmask) {
          if (jbase + n > prow) p0 = 0.f;
          if (jbase + 16 + n > prow) p1 = 0.f;
          if (jbase + 32 + n > prow) p2 = 0.f;
          if (jbase + 48 + n > prow) p3 = 0.f;
        }
        int sw = prow & 7;
        Ps[prow * 64 + (((0 + hi) ^ sw) << 3) + lo] = f2bf(p0);
        Ps[prow * 64 + (((2 + hi) ^ sw) << 3) + lo] = f2bf(p1);
        Ps[prow * 64 + (((4 + hi) ^ sw) << 3) + lo] = f2bf(p2);
        Ps[prow * 64 + (((6 + hi) ^ sw) << 3) + lo] = f2bf(p3);
      }
    }
    __asm__ volatile("s_waitcnt lgkmcnt(0)" ::: "memory");  // own-wave Ps visible

    // O += P V ; Ol += P @ ones  (vf shared across both m-tiles)
#pragma unroll
    for (int ks = 0; ks < 2; ++ks) {
      int r0 = 32 * w + n, r1 = 32 * w + 16 + n;
      short8 pf0 = *(const short8*)(Ps + r0 * 64 + (((4 * ks + quad) ^ (r0 & 7)) << 3));
      short8 pf1 = *(const short8*)(Ps + r1 * 64 + (((4 * ks + quad) ^ (r1 & 7)) << 3));
      Ol[0] = __builtin_amdgcn_mfma_f32_16x16x32_bf16(pf0, lfrag, Ol[0], 0, 0, 0);
      Ol[1] = __builtin_amdgcn_mfma_f32_16x16x32_bf16(pf1, lfrag, Ol[1], 0, 0, 0);
#pragma unroll
      for (int dt = 0; dt < 8; ++dt) {
        int d = 16 * dt + n;
        short8 vf = *(const short8*)(Vt + d * 64 + (((4 * ks + quad) ^ (d & 7)) << 3));
        O[0][dt] = __builtin_amdgcn_mfma_f32_16x16x32_bf16(pf0, vf, O[0][dt], 0, 0, 0);
        O[1][dt] = __builtin_amdgcn_mfma_f32_16x16x32_bf16(pf1, vf, O[1][dt], 0, 0, 0);
      }
    }
  }

  // epilogue: l broadcast, normalize, gate, store bf16
#pragma unroll
  for (int mt = 0; mt < 2; ++mt) {
#pragma unroll
    for (int r = 0; r < 4; ++r) {
      float l = __shfl(Ol[mt][r], quad << 4, 64);
      float inv = 1.0f / l;
      int row = q0 + 32 * w + 16 * mt + quad * 4 + r;
#pragma unroll
      for (int dt = 0; dt < 8; ++dt) {
        int col = 16 * dt + n;
        float gte = qkvf[(long)row * kNqkv + 256 * h + 128 + col];
        og[(long)row * kHid + 128 * h + col] = f2bf(O[mt][dt][r] * inv * gte);
      }
    }
  }
}

extern "C" void kernel_launch(void* const* d_in, const int* in_sizes, int n_in,
                              void* d_out, int out_size, void* d_ws, size_t ws_size,
                              hipStream_t stream) {
  (void)in_sizes; (void)n_in; (void)out_size; (void)ws_size;
  const float* hs   = (const float*)d_in[0];
  const float* cosb = (const float*)d_in[1];
  const float* sinb = (const float*)d_in[2];
  const float* wqkv = (const float*)d_in[3];
  const float* wo   = (const float*)d_in[4];
  const float* qw   = (const float*)d_in[5];
  const float* kw   = (const float*)d_in[6];
  float* out = (float*)d_out;

  char* ws = (char*)d_ws;
  float* qkv = (float*)ws;                                    // 75.5 MB fp32
  unsigned short* hsb = (unsigned short*)(ws + 75497472);     // 16.8 MB (aliases og)
  unsigned short* og  = hsb;                                  // written after hsb dead
  unsigned short* wt  = (unsigned short*)(ws + 92274688);     // 18.9 MB shared
  unsigned short* VtG = wt;  // aliases dead w_qkv^T during flash (w_o^T written after)

  prep_inputs<<<dim3(17408), 256, 0, stream>>>(hs, hsb, wqkv, wt);
  gemm_bf16<<<dim3(kT / 128, kNqkv / 128), 256, 0, stream>>>(hsb, wt, qkv, kT, kNqkv, kHid);
  vt_rope<<<dim3(3328), 256, 0, stream>>>(qkv, VtG, cosb, sinb, qw, kw);
  flash_attn_mfma<<<dim3(kT / 128 * kH), 256, 0, stream>>>((const unsigned short*)qkv, qkv, VtG, og);
  transpose_cvt<<<dim3(kHid / 32, kHid / 32), 256, 0, stream>>>(wo, wt, kHid, kHid);
  gemm_bf16<<<dim3(kT / 128, kHid / 128), 256, 0, stream>>>(og, wt, out, kT, kHid, kHid);
}

// Round 17
// 470.811 us; speedup vs baseline: 1.2097x; 1.0124x over previous
//
#include <hip/hip_runtime.h>
#include <hip/hip_bf16.h>
#include <math.h>

// Qwen3.5 attention block, bf16-MFMA everywhere. 5 dispatches:
// prep_inputs (cvt(hs) + transpose_cvt(w_qkv)) -> gemm_bf16(QKV) ->
// vt_rope (vt_transpose + norm_rope + transpose_cvt(w_o)) ->
// flash_attn_mfma v10 -> gemm_bf16(out).
//
// Structural notes (session evidence, 16 rounds):
// - 128^2 GEMM tile is grid-optimal for these shapes; 256^2 grids quantize
//   badly (288 blocks / 256 CUs at 1 blk/CU = 56% util): refuted r12/r13.
// - flash: per-tile cost saturates ~2.5us/tile/CU regardless of TLP;
//   barrier-removal via dedicated Ps was the structural win. Split-K,
//   dbuf, pairing, BN/BM scaling, L2-direct: all refuted with counters.
// - __expf lowers to v_mul+v_exp (fast path); exp2f is precise-path (r14).
// - Dispatch fusion r16: 8->6 kernels = -5.9us. This round: 6->5.
// - w_o^T relocated to wt+8MB (VtG needs only wt[0,2MB); w_qkv^T dead
//   after QKV gemm) so the w_o transpose can run inside vt_rope.

namespace {
constexpr int kT   = 4096;
constexpr int kHid = 2048;
constexpr int kH   = 16;
constexpr int kHkv = 2;
constexpr int kD   = 128;
constexpr int kNqkv = (2 * kH + 2 * kHkv) * kD;  // 4608 floats per row
constexpr int kQsz  = 2 * kH * kD;               // 4096
constexpr int kRowU = kNqkv * 2;                 // 9216 ushorts per row
constexpr float kEps = 1e-6f;
constexpr float kScale = 0.08838834764831845f;   // 128^-0.5
}

typedef __attribute__((ext_vector_type(8))) short short8;
typedef __attribute__((ext_vector_type(4))) float floatx4;

__device__ inline unsigned short f2bf(float x) {
  unsigned u = __float_as_uint(x);
  u = (u + 0x7fffu + ((u >> 16) & 1u)) >> 16;
  return (unsigned short)u;
}

__device__ inline void gload_lds16(const void* g, void* l) {
  typedef const __attribute__((address_space(1))) unsigned GQ;
  typedef __attribute__((address_space(3))) unsigned LQ;
  __builtin_amdgcn_global_load_lds((GQ*)g, (LQ*)l, 16, 0, 0);
}

// ---- fused: cvt_bf16(hs) [blocks 0..8191] +
//             transpose_cvt(w_qkv 2048x4608 -> wt 4608x2048) [8192..17407] ----
__global__ __launch_bounds__(256)
void prep_inputs(const float* __restrict__ hs, unsigned short* __restrict__ hsb,
                 const float* __restrict__ wqkv, unsigned short* __restrict__ wt) {
  __shared__ float t[32][33];
  const int b = blockIdx.x;
  if (b < 8192) {
    long i = ((long)b * 256 + threadIdx.x) * 4;
    float4 v = *(const float4*)(hs + i);
    unsigned long long p = (unsigned long long)f2bf(v.x) |
                           ((unsigned long long)f2bf(v.y) << 16) |
                           ((unsigned long long)f2bf(v.z) << 32) |
                           ((unsigned long long)f2bf(v.w) << 48);
    *(unsigned long long*)(hsb + i) = p;
    return;
  }
  const int b2 = b - 8192;                  // 0..9215
  const int bx = (b2 % 144) * 32;           // col tile in w_qkv
  const int by = (b2 / 144) * 32;           // row tile
  const int x = threadIdx.x & 31, y = threadIdx.x >> 5;
#pragma unroll
  for (int j = 0; j < 4; ++j)
    t[y * 4 + j][x] = wqkv[(long)(by + y * 4 + j) * kNqkv + bx + x];
  __syncthreads();
#pragma unroll
  for (int j = 0; j < 4; ++j)
    wt[(long)(bx + y * 4 + j) * kHid + by + x] = f2bf(t[x][y * 4 + j]);
}

// ---- C[M,N] fp32 = A[M,K]bf16 @ Bt[N,K]bf16^T. 128x128 tile, BK=64. ----
// XCD-band swizzle (kept from best build).
__global__ __launch_bounds__(256)
void gemm_bf16(const unsigned short* __restrict__ A,
               const unsigned short* __restrict__ Bt, float* __restrict__ C,
               int M, int N, int K) {
  __shared__ __align__(16) unsigned short As[128 * 64];
  __shared__ __align__(16) unsigned short Bs[128 * 64];
  const int tid = threadIdx.x;
  const int lane = tid & 63;
  const int w = tid >> 6;
  const int wr = w >> 1, wc = w & 1;
  const int n = lane & 15;
  const int quad = lane >> 4;

  int bx = blockIdx.x, by = blockIdx.y;
  const int nbx = gridDim.x, nby = gridDim.y;
  if (nbx == 32 && ((nbx * nby) & 7) == 0) {
    int lin = bx + nbx * by;        // dispatch-linear id (x fastest)
    int xcd = lin & 7, s = lin >> 3;
    bx = 4 * xcd + (s & 3);
    by = s >> 2;
  }
  const long bm = (long)bx * 128, bn = (long)by * 128;

  floatx4 acc[4][4];
  floatx4 zero = {0.f, 0.f, 0.f, 0.f};
#pragma unroll
  for (int a = 0; a < 4; ++a)
#pragma unroll
    for (int b = 0; b < 4; ++b) acc[a][b] = zero;

  for (int k0 = 0; k0 < K; k0 += 64) {
    __syncthreads();
#pragma unroll
    for (int it = 0; it < 4; ++it) {
      int ci = it * 256 + tid;            // 16B chunk id 0..1023
      int r = ci >> 3, c = ci & 7;
      int cg = c ^ (r & 7);               // global chunk for this slot
      gload_lds16(A + (bm + r) * (long)K + k0 + cg * 8, As + (it * 256 + w * 64) * 8);
      gload_lds16(Bt + (bn + r) * (long)K + k0 + cg * 8, Bs + (it * 256 + w * 64) * 8);
    }
    __syncthreads();

#pragma unroll
    for (int ks = 0; ks < 2; ++ks) {
      short8 af[4], bf[4];
#pragma unroll
      for (int a = 0; a < 4; ++a) {
        int m = wr * 64 + a * 16 + n;
        af[a] = *(const short8*)(As + m * 64 + ((4 * ks + quad) ^ (m & 7)) * 8);
      }
#pragma unroll
      for (int b = 0; b < 4; ++b) {
        int nn = wc * 64 + b * 16 + n;
        bf[b] = *(const short8*)(Bs + nn * 64 + ((4 * ks + quad) ^ (nn & 7)) * 8);
      }
#pragma unroll
      for (int a = 0; a < 4; ++a)
#pragma unroll
        for (int b = 0; b < 4; ++b)
          acc[a][b] = __builtin_amdgcn_mfma_f32_16x16x32_bf16(af[a], bf[b], acc[a][b], 0, 0, 0);
    }
  }
#pragma unroll
  for (int a = 0; a < 4; ++a)
#pragma unroll
    for (int b = 0; b < 4; ++b)
#pragma unroll
      for (int r = 0; r < 4; ++r)
        C[(bm + wr * 64 + a * 16 + quad * 4 + r) * (long)N + bn + wc * 64 + b * 16 + n] =
            acc[a][b][r];
}

// ---- fused: vt_transpose [0..1023] + norm_rope [1024..3327] +
//             transpose_cvt(w_o 2048x2048 -> woT) [3328..7423] ----
// vt reads V fp32 cols 4352..4607 -> VtG (wt[0,2MB)); rope writes packed
// q/k bf16 + gate fp32; w_o transpose writes woT (wt+8MB, dead w_qkv^T).
// All outputs disjoint -> safe single dispatch.
__global__ __launch_bounds__(256)
void vt_rope(float* qkv, unsigned short* __restrict__ VtG,
             const float* __restrict__ cosb, const float* __restrict__ sinb,
             const float* __restrict__ qw, const float* __restrict__ kw,
             const float* __restrict__ wo, unsigned short* __restrict__ woT) {
  __shared__ float t[32][33];
  const int b = blockIdx.x;
  if (b < 1024) {
    const int t0 = (b & 127) * 32;
    const int c0 = (b >> 7) * 32;
    const int x = threadIdx.x & 31, y = threadIdx.x >> 5;
#pragma unroll
    for (int j = 0; j < 4; ++j)
      t[y * 4 + j][x] = qkv[(long)(t0 + y * 4 + j) * kNqkv + 4352 + c0 + x];
    __syncthreads();
#pragma unroll
    for (int j = 0; j < 4; ++j)
      VtG[(long)(c0 + y * 4 + j) * kT + t0 + x] = f2bf(t[x][y * 4 + j]);
    return;
  }
  if (b >= 3328) {                        // w_o transpose: 64x64 tiles
    const int b3 = b - 3328;              // 0..4095
    const int bx = (b3 & 63) * 32;
    const int by = (b3 >> 6) * 32;
    const int x = threadIdx.x & 31, y = threadIdx.x >> 5;
#pragma unroll
    for (int j = 0; j < 4; ++j)
      t[y * 4 + j][x] = wo[(long)(by + y * 4 + j) * kHid + bx + x];
    __syncthreads();
#pragma unroll
    for (int j = 0; j < 4; ++j)
      woT[(long)(bx + y * 4 + j) * kHid + by + x] = f2bf(t[x][y * 4 + j]);
    return;
  }
  unsigned short* qkvu = (unsigned short*)qkv;
  const int lane = threadIdx.x & 63;
  const int wslot = (b - 1024) * 4 + (threadIdx.x >> 6);
  const int nslots = 2304 * 4;
  for (int task = wslot; task < kT * 18; task += nslots) {
    const int tt = task / 18;
    const int h = task % 18;
    const bool isq = (h < kH);
    const long base = (long)tt * kNqkv + (isq ? h * 2 * kD : kQsz + (h - kH) * kD);
    float xlo = qkv[base + lane];
    float xhi = qkv[base + 64 + lane];
    float v = xlo * xlo + xhi * xhi;
#pragma unroll
    for (int off = 1; off < 64; off <<= 1) v += __shfl_xor(v, off, 64);
    float rms = rsqrtf(v * (1.0f / kD) + kEps);
    const float* wv = isq ? qw : kw;
    float nlo = xlo * rms * wv[lane];
    float nhi = xhi * rms * wv[64 + lane];
    float clo = cosb[tt * kD + lane], chi = cosb[tt * kD + 64 + lane];
    float slo = sinb[tt * kD + lane], shi = sinb[tt * kD + 64 + lane];
    float rlo = nlo * clo - nhi * slo;   // rot(lo) = -x[l+64]
    float rhi = nhi * chi + nlo * shi;   // rot(hi) = +x[l]
    if (isq) {
      float glo = qkv[base + kD + lane];
      float ghi = qkv[base + kD + 64 + lane];
      qkv[base + kD + lane] = 1.0f / (1.0f + __expf(-glo));
      qkv[base + kD + 64 + lane] = 1.0f / (1.0f + __expf(-ghi));
      qkvu[(long)tt * kRowU + 512 * h + lane] = f2bf(rlo);
      qkvu[(long)tt * kRowU + 512 * h + 64 + lane] = f2bf(rhi);
    } else {
      qkvu[(long)tt * kRowU + 8192 + 256 * (h - kH) + lane] = f2bf(rlo);
      qkvu[(long)tt * kRowU + 8192 + 256 * (h - kH) + 64 + lane] = f2bf(rhi);
    }
  }
}

// ---------------- bf16 MFMA flash attention v10 (best: 165-167us) -----------
// v3 structure + dedicated Ps buffer (barrier (3) removed; 2 barriers/tile).
__global__ __launch_bounds__(256)
void flash_attn_mfma(const unsigned short* qkvu, const float* qkvf,
                     const unsigned short* VtG, unsigned short* __restrict__ og) {
  __shared__ __align__(16) unsigned short Ks[64 * 128];  // K tile (swizzled)
  __shared__ __align__(16) unsigned short Vt[128 * 64];  // V^T tile (swizzled)
  __shared__ __align__(16) unsigned short Ps[128 * 64];  // P tile (row-swizzled)

  const int tid = threadIdx.x;
  const int lane = tid & 63;
  const int w = tid >> 6;
  const int n = lane & 15;
  const int quad = lane >> 4;
  const int g = blockIdx.x;
  const int h = g & 15;
  const int bm = 31 - (g >> 4);   // heavy-first
  const int hk = h >> 3;
  const int q0 = bm * 128;

  short8 qf[2][4];
#pragma unroll
  for (int mt = 0; mt < 2; ++mt) {
    const unsigned short* qrow =
        qkvu + (long)(q0 + 32 * w + 16 * mt + n) * kRowU + 512 * h;
#pragma unroll
    for (int ks = 0; ks < 4; ++ks)
      qf[mt][ks] = *(const short8*)(qrow + 32 * ks + 8 * quad);
  }
  short8 lfrag;  // B-frag: col 0 = ones -> row-sum accumulator
  {
    short o = (n == 0) ? (short)0x3F80 : (short)0;
    lfrag = (short8){o, o, o, o, o, o, o, o};
  }

  floatx4 O[2][8];
  floatx4 Ol[2];
  floatx4 zero = {0.f, 0.f, 0.f, 0.f};
#pragma unroll
  for (int mt = 0; mt < 2; ++mt) {
    Ol[mt] = zero;
#pragma unroll
    for (int dt = 0; dt < 8; ++dt) O[mt][dt] = zero;
  }

  const int kn_end = 2 * bm + 1;
  for (int kn = 0; kn <= kn_end; ++kn) {
    __syncthreads();  // (1) prev QK+PV reads done before restage
    // stage K: 64 rows x 128 d, chunk swizzle c ^ (r&15)
#pragma unroll
    for (int it = 0; it < 4; ++it) {
      int pc = (w * 4 + it) * 64 + lane;
      int r = pc >> 4, c = pc & 15;
      int lc = c ^ (r & 15);
      gload_lds16(qkvu + (long)(kn * 64 + r) * kRowU + 8192 + 256 * hk + 8 * lc,
                  Ks + (w * 4 + it) * 512);
    }
    // stage V^T: 128 rows (d) x 64 keys, chunk swizzle c ^ (d&7)
#pragma unroll
    for (int it = 0; it < 4; ++it) {
      int pc = (w * 4 + it) * 64 + lane;
      int d = pc >> 3, c = pc & 7;
      int lc = c ^ (d & 7);
      gload_lds16(VtG + (long)hk * (128 * kT) + (long)d * kT + kn * 64 + 8 * lc,
                  Vt + (w * 4 + it) * 512);
    }
    __syncthreads();  // (2) staging complete

    // S = Q K^T  (kf shared across both m-tiles)
    floatx4 S[2][4];
#pragma unroll
    for (int mt = 0; mt < 2; ++mt)
#pragma unroll
      for (int ct = 0; ct < 4; ++ct) S[mt][ct] = zero;
#pragma unroll
    for (int ks = 0; ks < 4; ++ks) {
#pragma unroll
      for (int ct = 0; ct < 4; ++ct) {
        int row = 16 * ct + n;
        short8 kf = *(const short8*)(Ks + row * 128 + ((4 * ks + quad) ^ n) * 8);
        S[0][ct] = __builtin_amdgcn_mfma_f32_16x16x32_bf16(qf[0][ks], kf, S[0][ct], 0, 0, 0);
        S[1][ct] = __builtin_amdgcn_mfma_f32_16x16x32_bf16(qf[1][ks], kf, S[1][ct], 0, 0, 0);
      }
    }
    // no barrier: Ps is a separate buffer, each wave's rows are private

    // p = exp(s*scale); write Ps (128 rows x 64 cols, row-swizzled)
    const bool needmask = (kn >= 2 * bm);
    const int jbase = (kn - 2 * bm) * 64;
    const int hi = n >> 3, lo = n & 7;
#pragma unroll
    for (int mt = 0; mt < 2; ++mt) {
#pragma unroll
      for (int r = 0; r < 4; ++r) {
        int prow = 32 * w + 16 * mt + quad * 4 + r;
        float p0 = __expf(S[mt][0][r] * kScale);
        float p1 = __expf(S[mt][1][r] * kScale);
        float p2 = __expf(S[mt][2][r] * kScale);
        float p3 = __expf(S[mt][3][r] * kScale);
        if (needmask) {
          if (jbase + n > prow) p0 = 0.f;
          if (jbase + 16 + n > prow) p1 = 0.f;
          if (jbase + 32 + n > prow) p2 = 0.f;
          if (jbase + 48 + n > prow) p3 = 0.f;
        }
        int sw = prow & 7;
        Ps[prow * 64 + (((0 + hi) ^ sw) << 3) + lo] = f2bf(p0);
        Ps[prow * 64 + (((2 + hi) ^ sw) << 3) + lo] = f2bf(p1);
        Ps[prow * 64 + (((4 + hi) ^ sw) << 3) + lo] = f2bf(p2);
        Ps[prow * 64 + (((6 + hi) ^ sw) << 3) + lo] = f2bf(p3);
      }
    }
    __asm__ volatile("s_waitcnt lgkmcnt(0)" ::: "memory");  // own-wave Ps visible

    // O += P V ; Ol += P @ ones  (vf shared across both m-tiles)
#pragma unroll
    for (int ks = 0; ks < 2; ++ks) {
      int r0 = 32 * w + n, r1 = 32 * w + 16 + n;
      short8 pf0 = *(const short8*)(Ps + r0 * 64 + (((4 * ks + quad) ^ (r0 & 7)) << 3));
      short8 pf1 = *(const short8*)(Ps + r1 * 64 + (((4 * ks + quad) ^ (r1 & 7)) << 3));
      Ol[0] = __builtin_amdgcn_mfma_f32_16x16x32_bf16(pf0, lfrag, Ol[0], 0, 0, 0);
      Ol[1] = __builtin_amdgcn_mfma_f32_16x16x32_bf16(pf1, lfrag, Ol[1], 0, 0, 0);
#pragma unroll
      for (int dt = 0; dt < 8; ++dt) {
        int d = 16 * dt + n;
        short8 vf = *(const short8*)(Vt + d * 64 + (((4 * ks + quad) ^ (d & 7)) << 3));
        O[0][dt] = __builtin_amdgcn_mfma_f32_16x16x32_bf16(pf0, vf, O[0][dt], 0, 0, 0);
        O[1][dt] = __builtin_amdgcn_mfma_f32_16x16x32_bf16(pf1, vf, O[1][dt], 0, 0, 0);
      }
    }
  }

  // epilogue: l broadcast, normalize, gate, store bf16
#pragma unroll
  for (int mt = 0; mt < 2; ++mt) {
#pragma unroll
    for (int r = 0; r < 4; ++r) {
      float l = __shfl(Ol[mt][r], quad << 4, 64);
      float inv = 1.0f / l;
      int row = q0 + 32 * w + 16 * mt + quad * 4 + r;
#pragma unroll
      for (int dt = 0; dt < 8; ++dt) {
        int col = 16 * dt + n;
        float gte = qkvf[(long)row * kNqkv + 256 * h + 128 + col];
        og[(long)row * kHid + 128 * h + col] = f2bf(O[mt][dt][r] * inv * gte);
      }
    }
  }
}

extern "C" void kernel_launch(void* const* d_in, const int* in_sizes, int n_in,
                              void* d_out, int out_size, void* d_ws, size_t ws_size,
                              hipStream_t stream) {
  (void)in_sizes; (void)n_in; (void)out_size; (void)ws_size;
  const float* hs   = (const float*)d_in[0];
  const float* cosb = (const float*)d_in[1];
  const float* sinb = (const float*)d_in[2];
  const float* wqkv = (const float*)d_in[3];
  const float* wo   = (const float*)d_in[4];
  const float* qw   = (const float*)d_in[5];
  const float* kw   = (const float*)d_in[6];
  float* out = (float*)d_out;

  char* ws = (char*)d_ws;
  float* qkv = (float*)ws;                                    // 75.5 MB fp32
  unsigned short* hsb = (unsigned short*)(ws + 75497472);     // 16.8 MB (aliases og)
  unsigned short* og  = hsb;                                  // written after hsb dead
  unsigned short* wt  = (unsigned short*)(ws + 92274688);     // 18.9 MB shared
  unsigned short* VtG = wt;                     // wt[0, 2MB): V^T during flash
  unsigned short* woT = (unsigned short*)(ws + 92274688 + 8388608);  // wt+8MB

  prep_inputs<<<dim3(17408), 256, 0, stream>>>(hs, hsb, wqkv, wt);
  gemm_bf16<<<dim3(kT / 128, kNqkv / 128), 256, 0, stream>>>(hsb, wt, qkv, kT, kNqkv, kHid);
  vt_rope<<<dim3(7424), 256, 0, stream>>>(qkv, VtG, cosb, sinb, qw, kw, wo, woT);
  flash_attn_mfma<<<dim3(kT / 128 * kH), 256, 0, stream>>>((const unsigned short*)qkv, qkv, VtG, og);
  gemm_bf16<<<dim3(kT / 128, kHid / 128), 256, 0, stream>>>(og, woT, out, kT, kHid, kHid);
}

// Round 18
// 455.717 us; speedup vs baseline: 1.2498x; 1.0331x over previous
//
#include <hip/hip_runtime.h>
#include <hip/hip_bf16.h>
#include <math.h>

// Qwen3.5 attention block, bf16-MFMA everywhere. 5 dispatches:
// prep_inputs (cvt(hs) + transpose_cvt(w_qkv)) ->
// gemm_bf16 mode1 (QKV with FUSED RMSNorm+RoPE+pack / sigmoid-gate epilogue)
// -> vt_wo (V^T + w_o^T transposes) -> flash_attn_mfma v10 ->
// gemm_bf16 mode0 (out).
//
// Key trick this round: GEMM col remap col=(b&1)*64+(b>>1)*32+wc*16+n puts
// RoPE partner d^64 in the SAME LANE (acc[a][b^1][r]) -> rope needs zero
// data exchange; row-sums need only a 1KB LDS exchange (dead As) + 2 bars.
// Eliminates the rope HBM round-trip (~90MB) and its dispatch.
//
// Session evidence: 128^2 tile grid-optimal (256^2 refuted r12/r13); flash
// saturates ~2.5us/tile/CU regardless of TLP (all structural variants
// refuted); __expf = fast path, exp2f = precise path (r14); dispatch
// fusion r16/r17 = -6us each.

namespace {
constexpr int kT   = 4096;
constexpr int kHid = 2048;
constexpr int kH   = 16;
constexpr int kHkv = 2;
constexpr int kD   = 128;
constexpr int kNqkv = (2 * kH + 2 * kHkv) * kD;  // 4608 floats per row
constexpr int kQsz  = 2 * kH * kD;               // 4096
constexpr int kRowU = kNqkv * 2;                 // 9216 ushorts per row
constexpr float kEps = 1e-6f;
constexpr float kScale = 0.08838834764831845f;   // 128^-0.5
}

typedef __attribute__((ext_vector_type(8))) short short8;
typedef __attribute__((ext_vector_type(4))) float floatx4;

__device__ inline unsigned short f2bf(float x) {
  unsigned u = __float_as_uint(x);
  u = (u + 0x7fffu + ((u >> 16) & 1u)) >> 16;
  return (unsigned short)u;
}

__device__ inline void gload_lds16(const void* g, void* l) {
  typedef const __attribute__((address_space(1))) unsigned GQ;
  typedef __attribute__((address_space(3))) unsigned LQ;
  __builtin_amdgcn_global_load_lds((GQ*)g, (LQ*)l, 16, 0, 0);
}

// ---- fused: cvt_bf16(hs) [blocks 0..8191] +
//             transpose_cvt(w_qkv 2048x4608 -> wt 4608x2048) [8192..17407] ----
__global__ __launch_bounds__(256)
void prep_inputs(const float* __restrict__ hs, unsigned short* __restrict__ hsb,
                 const float* __restrict__ wqkv, unsigned short* __restrict__ wt) {
  __shared__ float t[32][33];
  const int b = blockIdx.x;
  if (b < 8192) {
    long i = ((long)b * 256 + threadIdx.x) * 4;
    float4 v = *(const float4*)(hs + i);
    unsigned long long p = (unsigned long long)f2bf(v.x) |
                           ((unsigned long long)f2bf(v.y) << 16) |
                           ((unsigned long long)f2bf(v.z) << 32) |
                           ((unsigned long long)f2bf(v.w) << 48);
    *(unsigned long long*)(hsb + i) = p;
    return;
  }
  const int b2 = b - 8192;                  // 0..9215
  const int bx = (b2 % 144) * 32;           // col tile in w_qkv
  const int by = (b2 / 144) * 32;           // row tile
  const int x = threadIdx.x & 31, y = threadIdx.x >> 5;
#pragma unroll
  for (int j = 0; j < 4; ++j)
    t[y * 4 + j][x] = wqkv[(long)(by + y * 4 + j) * kNqkv + bx + x];
  __syncthreads();
#pragma unroll
  for (int j = 0; j < 4; ++j)
    wt[(long)(bx + y * 4 + j) * kHid + by + x] = f2bf(t[x][y * 4 + j]);
}

// ---- C[M,N] fp32 = A[M,K]bf16 @ Bt[N,K]bf16^T. 128x128 tile, BK=64. ----
// Col mapping: local col = (b&1)*64 + (b>>1)*32 + wc*16 + n (d^64 <-> b^1).
// mode 0: standard fp32 C write. mode 1 (QKV): per-tile-class epilogue:
//   q tiles (bn<4096, bn%256==0):  RMSNorm+RoPE -> packed bf16 q
//   k tiles (4096<=bn<4352):       RMSNorm+RoPE -> packed bf16 k
//   gate tiles (bn<4096, bn%256==128): sigmoid -> fp32 C
//   V tiles (bn>=4352):            standard fp32 C write
__global__ __launch_bounds__(256)
void gemm_bf16(const unsigned short* __restrict__ A,
               const unsigned short* __restrict__ Bt, float* __restrict__ C,
               int M, int N, int K, int mode,
               const float* __restrict__ cosb, const float* __restrict__ sinb,
               const float* __restrict__ qw, const float* __restrict__ kw) {
  __shared__ __align__(16) unsigned short As[128 * 64];
  __shared__ __align__(16) unsigned short Bs[128 * 64];
  const int tid = threadIdx.x;
  const int lane = tid & 63;
  const int w = tid >> 6;
  const int wr = w >> 1, wc = w & 1;
  const int n = lane & 15;
  const int quad = lane >> 4;

  int bx = blockIdx.x, by = blockIdx.y;
  const int nbx = gridDim.x, nby = gridDim.y;
  if (nbx == 32 && ((nbx * nby) & 7) == 0) {
    int lin = bx + nbx * by;        // dispatch-linear id (x fastest)
    int xcd = lin & 7, s = lin >> 3;
    bx = 4 * xcd + (s & 3);
    by = s >> 2;
  }
  const long bm = (long)bx * 128, bn = (long)by * 128;

  floatx4 acc[4][4];
  floatx4 zero = {0.f, 0.f, 0.f, 0.f};
#pragma unroll
  for (int a = 0; a < 4; ++a)
#pragma unroll
    for (int b = 0; b < 4; ++b) acc[a][b] = zero;

  for (int k0 = 0; k0 < K; k0 += 64) {
    __syncthreads();
#pragma unroll
    for (int it = 0; it < 4; ++it) {
      int ci = it * 256 + tid;            // 16B chunk id 0..1023
      int r = ci >> 3, c = ci & 7;
      int cg = c ^ (r & 7);               // global chunk for this slot
      gload_lds16(A + (bm + r) * (long)K + k0 + cg * 8, As + (it * 256 + w * 64) * 8);
      gload_lds16(Bt + (bn + r) * (long)K + k0 + cg * 8, Bs + (it * 256 + w * 64) * 8);
    }
    __syncthreads();

#pragma unroll
    for (int ks = 0; ks < 2; ++ks) {
      short8 af[4], bf[4];
#pragma unroll
      for (int a = 0; a < 4; ++a) {
        int m = wr * 64 + a * 16 + n;
        af[a] = *(const short8*)(As + m * 64 + ((4 * ks + quad) ^ (m & 7)) * 8);
      }
#pragma unroll
      for (int b = 0; b < 4; ++b) {
        int nn = ((b & 1) << 6) + ((b >> 1) << 5) + wc * 16 + n;
        bf[b] = *(const short8*)(Bs + nn * 64 + ((4 * ks + quad) ^ (nn & 7)) * 8);
      }
#pragma unroll
      for (int a = 0; a < 4; ++a)
#pragma unroll
        for (int b = 0; b < 4; ++b)
          acc[a][b] = __builtin_amdgcn_mfma_f32_16x16x32_bf16(af[a], bf[b], acc[a][b], 0, 0, 0);
    }
  }

  const bool qkTile = (mode == 1) && (bn < 4352) && ((bn >= 4096) || !(bn & 128));
  const bool gateTile = (mode == 1) && (bn < 4096) && (bn & 128);
  if (qkTile) {
    // ---- fused RMSNorm + RoPE + bf16 pack ----
    __syncthreads();                       // all waves done reading As/Bs
    float* sums = (float*)As;              // [2 wc][128 rows] = 1KB
#pragma unroll
    for (int a = 0; a < 4; ++a)
#pragma unroll
      for (int r = 0; r < 4; ++r) {
        float s = 0.f;
#pragma unroll
        for (int b = 0; b < 4; ++b) { float v = acc[a][b][r]; s += v * v; }
#pragma unroll
        for (int off = 1; off < 16; off <<= 1) s += __shfl_xor(s, off, 64);
        if (n == 0) sums[wc * 128 + wr * 64 + a * 16 + quad * 4 + r] = s;
      }
    __syncthreads();
    const float* wv = (bn < 4096) ? qw : kw;
    const int hdOff = (bn < 4096) ? (int)(bn >> 8) * 512
                                  : 8192 + (int)((bn - 4096) >> 7) * 256;
    unsigned short* qkvu = (unsigned short*)C;
#pragma unroll
    for (int a = 0; a < 4; ++a)
#pragma unroll
      for (int r = 0; r < 4; ++r) {
        int lr = wr * 64 + a * 16 + quad * 4 + r;
        long t = bm + lr;
        float rms = rsqrtf((sums[lr] + sums[128 + lr]) * (1.0f / kD) + kEps);
        float nv[4];
#pragma unroll
        for (int b = 0; b < 4; ++b) {
          int d = ((b & 1) << 6) + ((b >> 1) << 5) + wc * 16 + n;
          nv[b] = acc[a][b][r] * rms * wv[d];
        }
#pragma unroll
        for (int b = 0; b < 4; ++b) {
          int d = ((b & 1) << 6) + ((b >> 1) << 5) + wc * 16 + n;
          float cv = cosb[t * kD + d], sv = sinb[t * kD + d];
          float p = nv[b ^ 1];
          float o = (b & 1) ? (nv[b] * cv + p * sv) : (nv[b] * cv - p * sv);
          qkvu[t * (long)kRowU + hdOff + d] = f2bf(o);
        }
      }
    return;
  }
  if (gateTile) {
#pragma unroll
    for (int a = 0; a < 4; ++a)
#pragma unroll
      for (int b = 0; b < 4; ++b) {
        int d = ((b & 1) << 6) + ((b >> 1) << 5) + wc * 16 + n;
#pragma unroll
        for (int r = 0; r < 4; ++r)
          C[(bm + wr * 64 + a * 16 + quad * 4 + r) * (long)N + bn + d] =
              1.0f / (1.0f + __expf(-acc[a][b][r]));
      }
    return;
  }
  // standard fp32 C write (mode 0, and V tiles of mode 1)
#pragma unroll
  for (int a = 0; a < 4; ++a)
#pragma unroll
    for (int b = 0; b < 4; ++b) {
      int d = ((b & 1) << 6) + ((b >> 1) << 5) + wc * 16 + n;
#pragma unroll
      for (int r = 0; r < 4; ++r)
        C[(bm + wr * 64 + a * 16 + quad * 4 + r) * (long)N + bn + d] =
            acc[a][b][r];
    }
}

// ---- fused: vt_transpose [0..1023] + transpose_cvt(w_o) [1024..5119] ----
__global__ __launch_bounds__(256)
void vt_wo(const float* __restrict__ qkv, unsigned short* __restrict__ VtG,
           const float* __restrict__ wo, unsigned short* __restrict__ woT) {
  __shared__ float t[32][33];
  const int b = blockIdx.x;
  const int x = threadIdx.x & 31, y = threadIdx.x >> 5;
  if (b < 1024) {
    const int t0 = (b & 127) * 32;
    const int c0 = (b >> 7) * 32;
#pragma unroll
    for (int j = 0; j < 4; ++j)
      t[y * 4 + j][x] = qkv[(long)(t0 + y * 4 + j) * kNqkv + 4352 + c0 + x];
    __syncthreads();
#pragma unroll
    for (int j = 0; j < 4; ++j)
      VtG[(long)(c0 + y * 4 + j) * kT + t0 + x] = f2bf(t[x][y * 4 + j]);
    return;
  }
  const int b3 = b - 1024;              // 0..4095
  const int bx = (b3 & 63) * 32;
  const int by = (b3 >> 6) * 32;
#pragma unroll
  for (int j = 0; j < 4; ++j)
    t[y * 4 + j][x] = wo[(long)(by + y * 4 + j) * kHid + bx + x];
  __syncthreads();
#pragma unroll
  for (int j = 0; j < 4; ++j)
    woT[(long)(bx + y * 4 + j) * kHid + by + x] = f2bf(t[x][y * 4 + j]);
}

// ---------------- bf16 MFMA flash attention v10 (best: 165-167us) -----------
// v3 structure + dedicated Ps buffer (barrier (3) removed; 2 barriers/tile).
__global__ __launch_bounds__(256)
void flash_attn_mfma(const unsigned short* qkvu, const float* qkvf,
                     const unsigned short* VtG, unsigned short* __restrict__ og) {
  __shared__ __align__(16) unsigned short Ks[64 * 128];  // K tile (swizzled)
  __shared__ __align__(16) unsigned short Vt[128 * 64];  // V^T tile (swizzled)
  __shared__ __align__(16) unsigned short Ps[128 * 64];  // P tile (row-swizzled)

  const int tid = threadIdx.x;
  const int lane = tid & 63;
  const int w = tid >> 6;
  const int n = lane & 15;
  const int quad = lane >> 4;
  const int g = blockIdx.x;
  const int h = g & 15;
  const int bm = 31 - (g >> 4);   // heavy-first
  const int hk = h >> 3;
  const int q0 = bm * 128;

  short8 qf[2][4];
#pragma unroll
  for (int mt = 0; mt < 2; ++mt) {
    const unsigned short* qrow =
        qkvu + (long)(q0 + 32 * w + 16 * mt + n) * kRowU + 512 * h;
#pragma unroll
    for (int ks = 0; ks < 4; ++ks)
      qf[mt][ks] = *(const short8*)(qrow + 32 * ks + 8 * quad);
  }
  short8 lfrag;  // B-frag: col 0 = ones -> row-sum accumulator
  {
    short o = (n == 0) ? (short)0x3F80 : (short)0;
    lfrag = (short8){o, o, o, o, o, o, o, o};
  }

  floatx4 O[2][8];
  floatx4 Ol[2];
  floatx4 zero = {0.f, 0.f, 0.f, 0.f};
#pragma unroll
  for (int mt = 0; mt < 2; ++mt) {
    Ol[mt] = zero;
#pragma unroll
    for (int dt = 0; dt < 8; ++dt) O[mt][dt] = zero;
  }

  const int kn_end = 2 * bm + 1;
  for (int kn = 0; kn <= kn_end; ++kn) {
    __syncthreads();  // (1) prev QK+PV reads done before restage
    // stage K: 64 rows x 128 d, chunk swizzle c ^ (r&15)
#pragma unroll
    for (int it = 0; it < 4; ++it) {
      int pc = (w * 4 + it) * 64 + lane;
      int r = pc >> 4, c = pc & 15;
      int lc = c ^ (r & 15);
      gload_lds16(qkvu + (long)(kn * 64 + r) * kRowU + 8192 + 256 * hk + 8 * lc,
                  Ks + (w * 4 + it) * 512);
    }
    // stage V^T: 128 rows (d) x 64 keys, chunk swizzle c ^ (d&7)
#pragma unroll
    for (int it = 0; it < 4; ++it) {
      int pc = (w * 4 + it) * 64 + lane;
      int d = pc >> 3, c = pc & 7;
      int lc = c ^ (d & 7);
      gload_lds16(VtG + (long)hk * (128 * kT) + (long)d * kT + kn * 64 + 8 * lc,
                  Vt + (w * 4 + it) * 512);
    }
    __syncthreads();  // (2) staging complete

    // S = Q K^T  (kf shared across both m-tiles)
    floatx4 S[2][4];
#pragma unroll
    for (int mt = 0; mt < 2; ++mt)
#pragma unroll
      for (int ct = 0; ct < 4; ++ct) S[mt][ct] = zero;
#pragma unroll
    for (int ks = 0; ks < 4; ++ks) {
#pragma unroll
      for (int ct = 0; ct < 4; ++ct) {
        int row = 16 * ct + n;
        short8 kf = *(const short8*)(Ks + row * 128 + ((4 * ks + quad) ^ n) * 8);
        S[0][ct] = __builtin_amdgcn_mfma_f32_16x16x32_bf16(qf[0][ks], kf, S[0][ct], 0, 0, 0);
        S[1][ct] = __builtin_amdgcn_mfma_f32_16x16x32_bf16(qf[1][ks], kf, S[1][ct], 0, 0, 0);
      }
    }
    // no barrier: Ps is a separate buffer, each wave's rows are private

    // p = exp(s*scale); write Ps (128 rows x 64 cols, row-swizzled)
    const bool needmask = (kn >= 2 * bm);
    const int jbase = (kn - 2 * bm) * 64;
    const int hi = n >> 3, lo = n & 7;
#pragma unroll
    for (int mt = 0; mt < 2; ++mt) {
#pragma unroll
      for (int r = 0; r < 4; ++r) {
        int prow = 32 * w + 16 * mt + quad * 4 + r;
        float p0 = __expf(S[mt][0][r] * kScale);
        float p1 = __expf(S[mt][1][r] * kScale);
        float p2 = __expf(S[mt][2][r] * kScale);
        float p3 = __expf(S[mt][3][r] * kScale);
        if (needmask) {
          if (jbase + n > prow) p0 = 0.f;
          if (jbase + 16 + n > prow) p1 = 0.f;
          if (jbase + 32 + n > prow) p2 = 0.f;
          if (jbase + 48 + n > prow) p3 = 0.f;
        }
        int sw = prow & 7;
        Ps[prow * 64 + (((0 + hi) ^ sw) << 3) + lo] = f2bf(p0);
        Ps[prow * 64 + (((2 + hi) ^ sw) << 3) + lo] = f2bf(p1);
        Ps[prow * 64 + (((4 + hi) ^ sw) << 3) + lo] = f2bf(p2);
        Ps[prow * 64 + (((6 + hi) ^ sw) << 3) + lo] = f2bf(p3);
      }
    }
    __asm__ volatile("s_waitcnt lgkmcnt(0)" ::: "memory");  // own-wave Ps visible

    // O += P V ; Ol += P @ ones  (vf shared across both m-tiles)
#pragma unroll
    for (int ks = 0; ks < 2; ++ks) {
      int r0 = 32 * w + n, r1 = 32 * w + 16 + n;
      short8 pf0 = *(const short8*)(Ps + r0 * 64 + (((4 * ks + quad) ^ (r0 & 7)) << 3));
      short8 pf1 = *(const short8*)(Ps + r1 * 64 + (((4 * ks + quad) ^ (r1 & 7)) << 3));
      Ol[0] = __builtin_amdgcn_mfma_f32_16x16x32_bf16(pf0, lfrag, Ol[0], 0, 0, 0);
      Ol[1] = __builtin_amdgcn_mfma_f32_16x16x32_bf16(pf1, lfrag, Ol[1], 0, 0, 0);
#pragma unroll
      for (int dt = 0; dt < 8; ++dt) {
        int d = 16 * dt + n;
        short8 vf = *(const short8*)(Vt + d * 64 + (((4 * ks + quad) ^ (d & 7)) << 3));
        O[0][dt] = __builtin_amdgcn_mfma_f32_16x16x32_bf16(pf0, vf, O[0][dt], 0, 0, 0);
        O[1][dt] = __builtin_amdgcn_mfma_f32_16x16x32_bf16(pf1, vf, O[1][dt], 0, 0, 0);
      }
    }
  }

  // epilogue: l broadcast, normalize, gate, store bf16
#pragma unroll
  for (int mt = 0; mt < 2; ++mt) {
#pragma unroll
    for (int r = 0; r < 4; ++r) {
      float l = __shfl(Ol[mt][r], quad << 4, 64);
      float inv = 1.0f / l;
      int row = q0 + 32 * w + 16 * mt + quad * 4 + r;
#pragma unroll
      for (int dt = 0; dt < 8; ++dt) {
        int col = 16 * dt + n;
        float gte = qkvf[(long)row * kNqkv + 256 * h + 128 + col];
        og[(long)row * kHid + 128 * h + col] = f2bf(O[mt][dt][r] * inv * gte);
      }
    }
  }
}

extern "C" void kernel_launch(void* const* d_in, const int* in_sizes, int n_in,
                              void* d_out, int out_size, void* d_ws, size_t ws_size,
                              hipStream_t stream) {
  (void)in_sizes; (void)n_in; (void)out_size; (void)ws_size;
  const float* hs   = (const float*)d_in[0];
  const float* cosb = (const float*)d_in[1];
  const float* sinb = (const float*)d_in[2];
  const float* wqkv = (const float*)d_in[3];
  const float* wo   = (const float*)d_in[4];
  const float* qw   = (const float*)d_in[5];
  const float* kw   = (const float*)d_in[6];
  float* out = (float*)d_out;

  char* ws = (char*)d_ws;
  float* qkv = (float*)ws;                                    // 75.5 MB fp32
  unsigned short* hsb = (unsigned short*)(ws + 75497472);     // 16.8 MB (aliases og)
  unsigned short* og  = hsb;                                  // written after hsb dead
  unsigned short* wt  = (unsigned short*)(ws + 92274688);     // 18.9 MB shared
  unsigned short* VtG = wt;                     // wt[0, 2MB): V^T during flash
  unsigned short* woT = (unsigned short*)(ws + 92274688 + 8388608);  // wt+8MB

  prep_inputs<<<dim3(17408), 256, 0, stream>>>(hs, hsb, wqkv, wt);
  gemm_bf16<<<dim3(kT / 128, kNqkv / 128), 256, 0, stream>>>(
      hsb, wt, qkv, kT, kNqkv, kHid, 1, cosb, sinb, qw, kw);
  vt_wo<<<dim3(5120), 256, 0, stream>>>(qkv, VtG, wo, woT);
  flash_attn_mfma<<<dim3(kT / 128 * kH), 256, 0, stream>>>((const unsigned short*)qkv, qkv, VtG, og);
  gemm_bf16<<<dim3(kT / 128, kHid / 128), 256, 0, stream>>>(
      og, woT, out, kT, kHid, kHid, 0, nullptr, nullptr, nullptr, nullptr);
}